// Round 1
// baseline (404.858 us; speedup 1.0000x reference)
//
#include <hip/hip_runtime.h>

typedef __bf16 bf16_t;
typedef __bf16 bf16x8 __attribute__((ext_vector_type(8)));
typedef __bf16 bf16x4 __attribute__((ext_vector_type(4)));
typedef float f32x4 __attribute__((ext_vector_type(4)));
typedef unsigned int u32;

#define NTOK 2048   // B*L
#define LSEQ 1024
#define DMODEL 1024
#define DINNER 2048
#define NXD 96      // DT_RANK + 2*D_STATE
#define DTRANK 64
#define NC 32       // scan chunks per sequence
#define CL 32       // chunk length (NC*CL == LSEQ)

__device__ __forceinline__ void gload16(const void* g, void* l) {
  __builtin_amdgcn_global_load_lds((const __attribute__((address_space(1))) u32*)g,
                                   (__attribute__((address_space(3))) u32*)l, 16, 0, 0);
}

// ---------------- fp32 -> bf16 convert ----------------
__global__ __launch_bounds__(256) void k_cvt(const float* __restrict__ in, bf16_t* __restrict__ out, int n4) {
  int i = blockIdx.x * 256 + threadIdx.x;
  if (i < n4) {
    float4 v = reinterpret_cast<const float4*>(in)[i];
    bf16x4 o = { (bf16_t)v.x, (bf16_t)v.y, (bf16_t)v.z, (bf16_t)v.w };
    reinterpret_cast<bf16x4*>(out)[i] = o;
  }
}

// ---------------- LayerNorm -> bf16 ----------------
__global__ __launch_bounds__(256) void k_ln(const float* __restrict__ x, const float* __restrict__ w,
                                            const float* __restrict__ b, bf16_t* __restrict__ xn) {
  const int row = blockIdx.x;
  const int tid = threadIdx.x;
  float4 v = reinterpret_cast<const float4*>(x + (size_t)row * DMODEL)[tid];
  float s = v.x + v.y + v.z + v.w;
  float q = v.x*v.x + v.y*v.y + v.z*v.z + v.w*v.w;
#pragma unroll
  for (int o = 32; o > 0; o >>= 1) { s += __shfl_down(s, o); q += __shfl_down(q, o); }
  __shared__ float sh[8];
  int wv = tid >> 6;
  if ((tid & 63) == 0) { sh[wv] = s; sh[4 + wv] = q; }
  __syncthreads();
  if (tid == 0) {
    sh[0] = sh[0] + sh[1] + sh[2] + sh[3];
    sh[4] = sh[4] + sh[5] + sh[6] + sh[7];
  }
  __syncthreads();
  float mu = sh[0] * (1.f / DMODEL);
  float var = sh[4] * (1.f / DMODEL) - mu * mu;
  float rs = rsqrtf(var + 1e-5f);
  float4 w4 = reinterpret_cast<const float4*>(w)[tid];
  float4 b4 = reinterpret_cast<const float4*>(b)[tid];
  bf16x4 o = { (bf16_t)((v.x - mu) * rs * w4.x + b4.x),
               (bf16_t)((v.y - mu) * rs * w4.y + b4.y),
               (bf16_t)((v.z - mu) * rs * w4.z + b4.z),
               (bf16_t)((v.w - mu) * rs * w4.w + b4.w) };
  reinterpret_cast<bf16x4*>(xn + (size_t)row * DMODEL)[tid] = o;
}

// ---------------- 128x128 MFMA GEMM, C = A(MxK) * Bt(NxK)^T [+ resid] ----------------
template <bool RESID>
__global__ __launch_bounds__(256) void k_gemm128(const bf16_t* __restrict__ A, const bf16_t* __restrict__ Bt,
                                                 float* __restrict__ C, const float* __restrict__ R,
                                                 int N, int K) {
  __shared__ bf16_t As[128 * 32];
  __shared__ bf16_t Bs[128 * 32];
  const int tid = threadIdx.x;
  const int w = tid >> 6, lane = tid & 63;
  const int brow = blockIdx.y * 128, bcol = blockIdx.x * 128;
  const int wr = (w >> 1) * 64, wc = (w & 1) * 64;

  // staging: chunk p = (w*2+j)*64 + lane covers row p>>2, 8-elem col (p&3)*8
  int p0 = (w * 2) * 64 + lane;
  int p1 = (w * 2 + 1) * 64 + lane;
  const bf16_t* gA0 = A + (size_t)(brow + (p0 >> 2)) * K + (p0 & 3) * 8;
  const bf16_t* gA1 = A + (size_t)(brow + (p1 >> 2)) * K + (p1 & 3) * 8;
  const bf16_t* gB0 = Bt + (size_t)(bcol + (p0 >> 2)) * K + (p0 & 3) * 8;
  const bf16_t* gB1 = Bt + (size_t)(bcol + (p1 >> 2)) * K + (p1 & 3) * 8;
  bf16_t* lA0 = &As[(w * 2) * 512];
  bf16_t* lA1 = &As[(w * 2 + 1) * 512];
  bf16_t* lB0 = &Bs[(w * 2) * 512];
  bf16_t* lB1 = &Bs[(w * 2 + 1) * 512];

  f32x4 acc[4][4] = {};
  for (int kk = 0; kk < K; kk += 32) {
    __syncthreads();
    gload16(gA0 + kk, lA0);
    gload16(gA1 + kk, lA1);
    gload16(gB0 + kk, lB0);
    gload16(gB1 + kk, lB1);
    __syncthreads();
    bf16x8 af[4], bf[4];
#pragma unroll
    for (int m = 0; m < 4; ++m) {
      int r = wr + m * 16 + (lane & 15);
      af[m] = *reinterpret_cast<const bf16x8*>(&As[r * 32 + (lane >> 4) * 8]);
    }
#pragma unroll
    for (int n = 0; n < 4; ++n) {
      int r = wc + n * 16 + (lane & 15);
      bf[n] = *reinterpret_cast<const bf16x8*>(&Bs[r * 32 + (lane >> 4) * 8]);
    }
#pragma unroll
    for (int m = 0; m < 4; ++m)
#pragma unroll
      for (int n = 0; n < 4; ++n)
        acc[m][n] = __builtin_amdgcn_mfma_f32_16x16x32_bf16(af[m], bf[n], acc[m][n], 0, 0, 0);
  }

#pragma unroll
  for (int m = 0; m < 4; ++m) {
#pragma unroll
    for (int n = 0; n < 4; ++n) {
      int col = bcol + wc + n * 16 + (lane & 15);
#pragma unroll
      for (int r = 0; r < 4; ++r) {
        int row = brow + wr + m * 16 + ((lane >> 4) << 2) + r;
        float v = acc[m][n][r];
        if (RESID) v += R[(size_t)row * N + col];
        C[(size_t)row * N + col] = v;
      }
    }
  }
}

// ---------------- depthwise causal conv1d + SiLU ----------------
__global__ __launch_bounds__(256) void k_conv(const float* __restrict__ xz, const float* __restrict__ cw,
                                              const float* __restrict__ cb, float* __restrict__ xsf,
                                              bf16_t* __restrict__ xsB) {
  int gid = blockIdx.x * 256 + threadIdx.x;
  int c = gid & (DINNER - 1);
  int t = gid >> 11;
  int l = t & (LSEQ - 1);
  float4 w4 = reinterpret_cast<const float4*>(cw)[c];
  float wk[4] = { w4.x, w4.y, w4.z, w4.w };
  float v = cb[c];
#pragma unroll
  for (int k = 0; k < 4; ++k) {
    int ll = l + k - 3;
    if (ll >= 0) v += wk[k] * xz[(size_t)(t + k - 3) * 4096 + c];
  }
  float sv = v / (1.f + __expf(-v));
  xsf[(size_t)t * DINNER + c] = sv;
  xsB[(size_t)t * DINNER + c] = (bf16_t)sv;
}

// ---------------- x_proj: xdbl[2048][96] = xs(bf16) @ W_x^T ----------------
__global__ __launch_bounds__(64) void k_xproj(const bf16_t* __restrict__ A, const bf16_t* __restrict__ Bt,
                                              float* __restrict__ C) {
  int lane = threadIdx.x;
  int r0 = blockIdx.x * 16;
  int arow = r0 + (lane & 15);
  int kof = (lane >> 4) * 8;
  f32x4 acc[6] = {};
  for (int k = 0; k < DINNER; k += 32) {
    bf16x8 af = *reinterpret_cast<const bf16x8*>(A + (size_t)arow * DINNER + k + kof);
#pragma unroll
    for (int j = 0; j < 6; ++j) {
      bf16x8 bf = *reinterpret_cast<const bf16x8*>(Bt + (size_t)(j * 16 + (lane & 15)) * DINNER + k + kof);
      acc[j] = __builtin_amdgcn_mfma_f32_16x16x32_bf16(af, bf, acc[j], 0, 0, 0);
    }
  }
#pragma unroll
  for (int j = 0; j < 6; ++j) {
    int col = j * 16 + (lane & 15);
#pragma unroll
    for (int r = 0; r < 4; ++r) {
      int row = r0 + ((lane >> 4) << 2) + r;
      C[(size_t)row * NXD + col] = acc[j][r];
    }
  }
}

// ---------------- dt_proj (K=64) + softplus ----------------
__global__ __launch_bounds__(256) void k_dtproj(const float* __restrict__ xdbl, const bf16_t* __restrict__ Wdt,
                                                const float* __restrict__ bdt, float* __restrict__ dtf) {
  int tid = threadIdx.x, w = tid >> 6, lane = tid & 63;
  int r0 = blockIdx.y * 64 + w * 16;
  int c0 = blockIdx.x * 64;
  int arow = r0 + (lane & 15);
  int kof = (lane >> 4) * 8;
  f32x4 acc[4] = {};
#pragma unroll
  for (int ks = 0; ks < 2; ++ks) {
    int k = ks * 32;
    const float* ap = xdbl + (size_t)arow * NXD + k + kof;
    float4 a0 = *reinterpret_cast<const float4*>(ap);
    float4 a1 = *reinterpret_cast<const float4*>(ap + 4);
    bf16x8 af = { (bf16_t)a0.x, (bf16_t)a0.y, (bf16_t)a0.z, (bf16_t)a0.w,
                  (bf16_t)a1.x, (bf16_t)a1.y, (bf16_t)a1.z, (bf16_t)a1.w };
#pragma unroll
    for (int j = 0; j < 4; ++j) {
      bf16x8 bf = *reinterpret_cast<const bf16x8*>(Wdt + (size_t)(c0 + j * 16 + (lane & 15)) * DTRANK + k + kof);
      acc[j] = __builtin_amdgcn_mfma_f32_16x16x32_bf16(af, bf, acc[j], 0, 0, 0);
    }
  }
#pragma unroll
  for (int j = 0; j < 4; ++j) {
    int col = c0 + j * 16 + (lane & 15);
    float bb = bdt[col];
#pragma unroll
    for (int r = 0; r < 4; ++r) {
      int row = r0 + ((lane >> 4) << 2) + r;
      float v = acc[j][r] + bb;
      v = (v > 20.f) ? v : log1pf(__expf(v));
      dtf[(size_t)row * DINNER + col] = v;
    }
  }
}

// ---------------- scan pass A: per-chunk (prod dA, local h) ----------------
__global__ __launch_bounds__(256) void k_scanA(const float* __restrict__ dtf, const float* __restrict__ xsf,
                                               const float* __restrict__ xdbl, const float* __restrict__ A_log,
                                               float* __restrict__ Sp, float* __restrict__ Ss) {
  int gid = blockIdx.x * 256 + threadIdx.x;
  int c = gid & (DINNER - 1);
  int chunk = (gid >> 11) & (NC - 1);
  int b = gid >> 16;
  int t0 = b * LSEQ + chunk * CL;
  float a[16];
#pragma unroll
  for (int n = 0; n < 16; n += 4) {
    float4 al = reinterpret_cast<const float4*>(A_log + (size_t)c * 16)[n >> 2];
    a[n] = -__expf(al.x); a[n + 1] = -__expf(al.y); a[n + 2] = -__expf(al.z); a[n + 3] = -__expf(al.w);
  }
  float ap[16], h[16];
#pragma unroll
  for (int n = 0; n < 16; ++n) { ap[n] = 1.f; h[n] = 0.f; }
  for (int l = 0; l < CL; ++l) {
    int t = t0 + l;
    float dt = dtf[(size_t)t * DINNER + c];
    float xv = xsf[(size_t)t * DINNER + c];
    float dtx = dt * xv;
    const float4* bp = reinterpret_cast<const float4*>(xdbl + (size_t)t * NXD + DTRANK);
    float4 b0 = bp[0], b1 = bp[1], b2 = bp[2], b3 = bp[3];
    float bv[16] = { b0.x, b0.y, b0.z, b0.w, b1.x, b1.y, b1.z, b1.w,
                     b2.x, b2.y, b2.z, b2.w, b3.x, b3.y, b3.z, b3.w };
#pragma unroll
    for (int n = 0; n < 16; ++n) {
      float e = __expf(dt * a[n]);
      ap[n] *= e;
      h[n] = e * h[n] + dtx * bv[n];
    }
  }
  size_t base = ((size_t)(b * NC + chunk) * 16) * DINNER + c;
#pragma unroll
  for (int n = 0; n < 16; ++n) {
    Sp[base + (size_t)n * DINNER] = ap[n];
    Ss[base + (size_t)n * DINNER] = h[n];
  }
}

// ---------------- scan pass B: combine chunk summaries -> h_init per chunk ----------------
__global__ __launch_bounds__(256) void k_scanB(const float* __restrict__ Sp, const float* __restrict__ Ss,
                                               float* __restrict__ Hi) {
  int gid = blockIdx.x * 256 + threadIdx.x;  // 4096 threads
  int c = gid & (DINNER - 1);
  int b = gid >> 11;
  float h[16];
#pragma unroll
  for (int n = 0; n < 16; ++n) h[n] = 0.f;
  for (int chunk = 0; chunk < NC; ++chunk) {
    size_t base = ((size_t)(b * NC + chunk) * 16) * DINNER + c;
#pragma unroll
    for (int n = 0; n < 16; ++n) {
      Hi[base + (size_t)n * DINNER] = h[n];
      float p = Sp[base + (size_t)n * DINNER];
      float s = Ss[base + (size_t)n * DINNER];
      h[n] = p * h[n] + s;
    }
  }
}

// ---------------- scan pass C: replay with h_init, fuse y + gate -> y bf16 ----------------
__global__ __launch_bounds__(256) void k_scanC(const float* __restrict__ dtf, const float* __restrict__ xsf,
                                               const float* __restrict__ xdbl, const float* __restrict__ A_log,
                                               const float* __restrict__ Hi, const float* __restrict__ Dp,
                                               const float* __restrict__ xz, bf16_t* __restrict__ yB) {
  int gid = blockIdx.x * 256 + threadIdx.x;
  int c = gid & (DINNER - 1);
  int chunk = (gid >> 11) & (NC - 1);
  int b = gid >> 16;
  int t0 = b * LSEQ + chunk * CL;
  float a[16];
#pragma unroll
  for (int n = 0; n < 16; n += 4) {
    float4 al = reinterpret_cast<const float4*>(A_log + (size_t)c * 16)[n >> 2];
    a[n] = -__expf(al.x); a[n + 1] = -__expf(al.y); a[n + 2] = -__expf(al.z); a[n + 3] = -__expf(al.w);
  }
  float h[16];
  size_t base = ((size_t)(b * NC + chunk) * 16) * DINNER + c;
#pragma unroll
  for (int n = 0; n < 16; ++n) h[n] = Hi[base + (size_t)n * DINNER];
  float dpc = Dp[c];
  for (int l = 0; l < CL; ++l) {
    int t = t0 + l;
    float dt = dtf[(size_t)t * DINNER + c];
    float xv = xsf[(size_t)t * DINNER + c];
    float dtx = dt * xv;
    const float4* bp = reinterpret_cast<const float4*>(xdbl + (size_t)t * NXD + DTRANK);
    float4 b0 = bp[0], b1 = bp[1], b2 = bp[2], b3 = bp[3];
    float bv[16] = { b0.x, b0.y, b0.z, b0.w, b1.x, b1.y, b1.z, b1.w,
                     b2.x, b2.y, b2.z, b2.w, b3.x, b3.y, b3.z, b3.w };
    const float4* cp = reinterpret_cast<const float4*>(xdbl + (size_t)t * NXD + DTRANK + 16);
    float4 c0 = cp[0], c1 = cp[1], c2 = cp[2], c3 = cp[3];
    float cv[16] = { c0.x, c0.y, c0.z, c0.w, c1.x, c1.y, c1.z, c1.w,
                     c2.x, c2.y, c2.z, c2.w, c3.x, c3.y, c3.z, c3.w };
    float y = 0.f;
#pragma unroll
    for (int n = 0; n < 16; ++n) {
      float e = __expf(dt * a[n]);
      h[n] = e * h[n] + dtx * bv[n];
      y += h[n] * cv[n];
    }
    y += dpc * xv;
    float zv = xz[(size_t)t * 4096 + DINNER + c];
    y *= zv / (1.f + __expf(-zv));
    yB[(size_t)t * DINNER + c] = (bf16_t)y;
  }
}

extern "C" void kernel_launch(void* const* d_in, const int* in_sizes, int n_in,
                              void* d_out, int out_size, void* d_ws, size_t ws_size,
                              hipStream_t stream) {
  (void)in_sizes; (void)n_in; (void)out_size; (void)ws_size;
  const float* x      = (const float*)d_in[0];
  const float* ln_w   = (const float*)d_in[1];
  const float* ln_b   = (const float*)d_in[2];
  const float* W_in   = (const float*)d_in[3];
  const float* conv_w = (const float*)d_in[4];
  const float* conv_b = (const float*)d_in[5];
  const float* W_x    = (const float*)d_in[6];
  const float* W_dt   = (const float*)d_in[7];
  const float* b_dt   = (const float*)d_in[8];
  const float* A_log  = (const float*)d_in[9];
  const float* Dp     = (const float*)d_in[10];
  const float* W_out  = (const float*)d_in[11];
  float* out = (float*)d_out;

  char* ws = (char*)d_ws;
  size_t off = 0;
  auto alloc = [&](size_t bytes) { void* p = ws + off; off += (bytes + 255) & ~255ull; return p; };
  bf16_t* wInB  = (bf16_t*)alloc((size_t)4096 * 1024 * 2);
  bf16_t* wXB   = (bf16_t*)alloc((size_t)96 * 2048 * 2);
  bf16_t* wDtB  = (bf16_t*)alloc((size_t)2048 * 64 * 2);
  bf16_t* wOutB = (bf16_t*)alloc((size_t)1024 * 2048 * 2);
  bf16_t* xnB   = (bf16_t*)alloc((size_t)NTOK * DMODEL * 2);
  float*  xz    = (float*)alloc((size_t)NTOK * 4096 * 4);
  float*  xsf   = (float*)alloc((size_t)NTOK * DINNER * 4);
  bf16_t* xsB   = (bf16_t*)alloc((size_t)NTOK * DINNER * 2);
  float*  xdbl  = (float*)alloc((size_t)NTOK * NXD * 4);
  float*  dtf   = (float*)alloc((size_t)NTOK * DINNER * 4);
  float*  Sp    = (float*)alloc((size_t)2 * NC * 16 * DINNER * 4);
  float*  Ss    = (float*)alloc((size_t)2 * NC * 16 * DINNER * 4);
  float*  Hi    = (float*)alloc((size_t)2 * NC * 16 * DINNER * 4);
  bf16_t* yB    = (bf16_t*)alloc((size_t)NTOK * DINNER * 2);

  // weight conversions
  k_cvt<<<4096, 256, 0, stream>>>(W_in, wInB, 4096 * 1024 / 4);
  k_cvt<<<192, 256, 0, stream>>>(W_x, wXB, 96 * 2048 / 4);
  k_cvt<<<128, 256, 0, stream>>>(W_dt, wDtB, 2048 * 64 / 4);
  k_cvt<<<2048, 256, 0, stream>>>(W_out, wOutB, 1024 * 2048 / 4);

  // layernorm
  k_ln<<<NTOK, 256, 0, stream>>>(x, ln_w, ln_b, xnB);

  // in_proj: xz[2048][4096]
  k_gemm128<false><<<dim3(4096 / 128, NTOK / 128), 256, 0, stream>>>(xnB, wInB, xz, nullptr, 4096, 1024);

  // conv + silu
  k_conv<<<NTOK * DINNER / 256, 256, 0, stream>>>(xz, conv_w, conv_b, xsf, xsB);

  // x_proj
  k_xproj<<<NTOK / 16, 64, 0, stream>>>(xsB, wXB, xdbl);

  // dt_proj + softplus
  k_dtproj<<<dim3(DINNER / 64, NTOK / 64), 256, 0, stream>>>(xdbl, wDtB, b_dt, dtf);

  // chunked scan
  k_scanA<<<2 * NC * DINNER / 256, 256, 0, stream>>>(dtf, xsf, xdbl, A_log, Sp, Ss);
  k_scanB<<<2 * DINNER / 256, 256, 0, stream>>>(Sp, Ss, Hi);
  k_scanC<<<2 * NC * DINNER / 256, 256, 0, stream>>>(dtf, xsf, xdbl, A_log, Hi, Dp, xz, yB);

  // out_proj + residual
  k_gemm128<true><<<dim3(1024 / 128, NTOK / 128), 256, 0, stream>>>(yB, wOutB, out, x, 1024, 2048);
}

// Round 2
// 311.796 us; speedup vs baseline: 1.2985x; 1.2985x over previous
//
#include <hip/hip_runtime.h>

typedef __bf16 bf16_t;
typedef __bf16 bf16x8 __attribute__((ext_vector_type(8)));
typedef __bf16 bf16x4 __attribute__((ext_vector_type(4)));
typedef float f32x4 __attribute__((ext_vector_type(4)));
typedef unsigned int u32;

#define NTOK 2048   // B*L
#define LSEQ 1024
#define DMODEL 1024
#define DINNER 2048
#define NXD 96      // DT_RANK + 2*D_STATE
#define DTRANK 64
#define NC 32       // scan chunks per sequence
#define CL 32       // chunk length (NC*CL == LSEQ)

__device__ __forceinline__ void gload16(const void* g, void* l) {
  __builtin_amdgcn_global_load_lds((const __attribute__((address_space(1))) u32*)g,
                                   (__attribute__((address_space(3))) u32*)l, 16, 0, 0);
}

// ---------------- fused fp32 -> bf16 weight convert (4 arrays, 1 launch) ----------------
#define CVT_N0 1048576            // W_in  / 4
#define CVT_N1 (CVT_N0 + 49152)   // + W_x / 4
#define CVT_N2 (CVT_N1 + 32768)   // + W_dt / 4
#define CVT_N3 (CVT_N2 + 524288)  // + W_out / 4
__global__ __launch_bounds__(256) void k_cvt4(const float* __restrict__ a0, const float* __restrict__ a1,
                                              const float* __restrict__ a2, const float* __restrict__ a3,
                                              bf16_t* __restrict__ o0, bf16_t* __restrict__ o1,
                                              bf16_t* __restrict__ o2, bf16_t* __restrict__ o3) {
  int i = blockIdx.x * 256 + threadIdx.x;
  const float* src; bf16_t* dst; int idx;
  if (i < CVT_N0)      { src = a0; dst = o0; idx = i; }
  else if (i < CVT_N1) { src = a1; dst = o1; idx = i - CVT_N0; }
  else if (i < CVT_N2) { src = a2; dst = o2; idx = i - CVT_N1; }
  else if (i < CVT_N3) { src = a3; dst = o3; idx = i - CVT_N2; }
  else return;
  float4 v = reinterpret_cast<const float4*>(src)[idx];
  bf16x4 o = { (bf16_t)v.x, (bf16_t)v.y, (bf16_t)v.z, (bf16_t)v.w };
  reinterpret_cast<bf16x4*>(dst)[idx] = o;
}

// ---------------- LayerNorm -> bf16 ----------------
__global__ __launch_bounds__(256) void k_ln(const float* __restrict__ x, const float* __restrict__ w,
                                            const float* __restrict__ b, bf16_t* __restrict__ xn) {
  const int row = blockIdx.x;
  const int tid = threadIdx.x;
  float4 v = reinterpret_cast<const float4*>(x + (size_t)row * DMODEL)[tid];
  float s = v.x + v.y + v.z + v.w;
  float q = v.x*v.x + v.y*v.y + v.z*v.z + v.w*v.w;
#pragma unroll
  for (int o = 32; o > 0; o >>= 1) { s += __shfl_down(s, o); q += __shfl_down(q, o); }
  __shared__ float sh[8];
  int wv = tid >> 6;
  if ((tid & 63) == 0) { sh[wv] = s; sh[4 + wv] = q; }
  __syncthreads();
  if (tid == 0) {
    sh[0] = sh[0] + sh[1] + sh[2] + sh[3];
    sh[4] = sh[4] + sh[5] + sh[6] + sh[7];
  }
  __syncthreads();
  float mu = sh[0] * (1.f / DMODEL);
  float var = sh[4] * (1.f / DMODEL) - mu * mu;
  float rs = rsqrtf(var + 1e-5f);
  float4 w4 = reinterpret_cast<const float4*>(w)[tid];
  float4 b4 = reinterpret_cast<const float4*>(b)[tid];
  bf16x4 o = { (bf16_t)((v.x - mu) * rs * w4.x + b4.x),
               (bf16_t)((v.y - mu) * rs * w4.y + b4.y),
               (bf16_t)((v.z - mu) * rs * w4.z + b4.z),
               (bf16_t)((v.w - mu) * rs * w4.w + b4.w) };
  reinterpret_cast<bf16x4*>(xn + (size_t)row * DMODEL)[tid] = o;
}

// ---------------- BMx128 MFMA GEMM, C = A(MxK) * Bt(NxK)^T [+ resid], XCD-swizzled ----------------
template <int BM, bool RESID>
__global__ __launch_bounds__(256) void k_gemm(const bf16_t* __restrict__ A, const bf16_t* __restrict__ Bt,
                                              float* __restrict__ C, const float* __restrict__ R,
                                              int N, int K) {
  constexpr int BN = 128;
  constexpr int MR = BM / 32;          // acc m-repeat per wave (wave owns BM/2 rows x 64 cols)
  constexpr int NCHUNK = (BM + BN) * 4;
  constexpr int ITER = NCHUNK / 256;
  __shared__ bf16_t As[BM * 32];
  __shared__ bf16_t Bs[BN * 32];
  const int tid = threadIdx.x;
  const int w = tid >> 6, lane = tid & 63;

  // XCD-aware swizzle (nwg % 8 == 0 for all our launches)
  const int nbx = gridDim.x;
  int nwg = gridDim.x * gridDim.y;
  int orig = blockIdx.y * gridDim.x + blockIdx.x;
  int cpx = nwg >> 3;
  int swz = (orig & 7) * cpx + (orig >> 3);
  int bx = swz % nbx, by = swz / nbx;
  const int brow = by * BM, bcol = bx * BN;
  const int wr = (w >> 1) * (BM / 2), wc = (w & 1) * 64;

  // staging: chunk p covers 16B = 8 elems; rows have 4 chunks of K=32
  const bf16_t* gsrc[ITER];
  bf16_t* lbase[ITER];
#pragma unroll
  for (int i = 0; i < ITER; ++i) {
    int p0 = i * 256 + w * 64;          // wave-uniform chunk base
    int p = p0 + lane;
    if (p0 < BM * 4) {
      gsrc[i] = A + (size_t)(brow + (p >> 2)) * K + (p & 3) * 8;
      lbase[i] = &As[p0 * 8];
    } else {
      int q = p - BM * 4, q0 = p0 - BM * 4;
      gsrc[i] = Bt + (size_t)(bcol + (q >> 2)) * K + (q & 3) * 8;
      lbase[i] = &Bs[q0 * 8];
    }
  }

  f32x4 acc[MR][4] = {};
  for (int kk = 0; kk < K; kk += 32) {
    __syncthreads();
#pragma unroll
    for (int i = 0; i < ITER; ++i) gload16(gsrc[i] + kk, lbase[i]);
    __syncthreads();
    bf16x8 af[MR], bfr[4];
#pragma unroll
    for (int m = 0; m < MR; ++m)
      af[m] = *reinterpret_cast<const bf16x8*>(&As[(wr + m * 16 + (lane & 15)) * 32 + (lane >> 4) * 8]);
#pragma unroll
    for (int n = 0; n < 4; ++n)
      bfr[n] = *reinterpret_cast<const bf16x8*>(&Bs[(wc + n * 16 + (lane & 15)) * 32 + (lane >> 4) * 8]);
#pragma unroll
    for (int m = 0; m < MR; ++m)
#pragma unroll
      for (int n = 0; n < 4; ++n)
        acc[m][n] = __builtin_amdgcn_mfma_f32_16x16x32_bf16(af[m], bfr[n], acc[m][n], 0, 0, 0);
  }

#pragma unroll
  for (int m = 0; m < MR; ++m) {
#pragma unroll
    for (int n = 0; n < 4; ++n) {
      int col = bcol + wc + n * 16 + (lane & 15);
#pragma unroll
      for (int r = 0; r < 4; ++r) {
        int row = brow + wr + m * 16 + ((lane >> 4) << 2) + r;
        float v = acc[m][n][r];
        if (RESID) v += R[(size_t)row * N + col];
        C[(size_t)row * N + col] = v;
      }
    }
  }
}

// ---------------- depthwise causal conv1d + SiLU ----------------
__global__ __launch_bounds__(256) void k_conv(const float* __restrict__ xz, const float* __restrict__ cw,
                                              const float* __restrict__ cb, float* __restrict__ xsf,
                                              bf16_t* __restrict__ xsB) {
  int gid = blockIdx.x * 256 + threadIdx.x;
  int c = gid & (DINNER - 1);
  int t = gid >> 11;
  int l = t & (LSEQ - 1);
  float4 w4 = reinterpret_cast<const float4*>(cw)[c];
  float wk[4] = { w4.x, w4.y, w4.z, w4.w };
  float v = cb[c];
#pragma unroll
  for (int k = 0; k < 4; ++k) {
    int ll = l + k - 3;
    if (ll >= 0) v += wk[k] * xz[(size_t)(t + k - 3) * 4096 + c];
  }
  float sv = v / (1.f + __expf(-v));
  xsf[(size_t)t * DINNER + c] = sv;
  xsB[(size_t)t * DINNER + c] = (bf16_t)sv;
}

// ---------------- x_proj: xdbl[2048][96] = xs(bf16) @ W_x^T, K split across 4 waves ----------------
__global__ __launch_bounds__(256) void k_xproj(const bf16_t* __restrict__ A, const bf16_t* __restrict__ Bt,
                                               float* __restrict__ C) {
  __shared__ f32x4 red[4][6][64];
  int tid = threadIdx.x, w = tid >> 6, lane = tid & 63;
  int r0 = blockIdx.x * 16;
  int arow = r0 + (lane & 15);
  int kof = (lane >> 4) * 8;
  f32x4 acc[6] = {};
  for (int k = w * 512; k < (w + 1) * 512; k += 32) {
    bf16x8 af = *reinterpret_cast<const bf16x8*>(A + (size_t)arow * DINNER + k + kof);
#pragma unroll
    for (int j = 0; j < 6; ++j) {
      bf16x8 bfr = *reinterpret_cast<const bf16x8*>(Bt + (size_t)(j * 16 + (lane & 15)) * DINNER + k + kof);
      acc[j] = __builtin_amdgcn_mfma_f32_16x16x32_bf16(af, bfr, acc[j], 0, 0, 0);
    }
  }
#pragma unroll
  for (int j = 0; j < 6; ++j) red[w][j][lane] = acc[j];
  __syncthreads();
  for (int item = tid; item < 384; item += 256) {
    int j = item >> 6, li = item & 63;
    f32x4 s = red[0][j][li];
#pragma unroll
    for (int ww = 1; ww < 4; ++ww) s += red[ww][j][li];
    int col = j * 16 + (li & 15);
    int rowb = r0 + ((li >> 4) << 2);
#pragma unroll
    for (int r = 0; r < 4; ++r) C[(size_t)(rowb + r) * NXD + col] = s[r];
  }
}

// ---------------- dt_proj (K=64) + softplus ----------------
__global__ __launch_bounds__(256) void k_dtproj(const float* __restrict__ xdbl, const bf16_t* __restrict__ Wdt,
                                                const float* __restrict__ bdt, float* __restrict__ dtf) {
  int tid = threadIdx.x, w = tid >> 6, lane = tid & 63;
  int r0 = blockIdx.y * 64 + w * 16;
  int c0 = blockIdx.x * 64;
  int arow = r0 + (lane & 15);
  int kof = (lane >> 4) * 8;
  f32x4 acc[4] = {};
#pragma unroll
  for (int ks = 0; ks < 2; ++ks) {
    int k = ks * 32;
    const float* ap = xdbl + (size_t)arow * NXD + k + kof;
    float4 a0 = *reinterpret_cast<const float4*>(ap);
    float4 a1 = *reinterpret_cast<const float4*>(ap + 4);
    bf16x8 af = { (bf16_t)a0.x, (bf16_t)a0.y, (bf16_t)a0.z, (bf16_t)a0.w,
                  (bf16_t)a1.x, (bf16_t)a1.y, (bf16_t)a1.z, (bf16_t)a1.w };
#pragma unroll
    for (int j = 0; j < 4; ++j) {
      bf16x8 bfr = *reinterpret_cast<const bf16x8*>(Wdt + (size_t)(c0 + j * 16 + (lane & 15)) * DTRANK + k + kof);
      acc[j] = __builtin_amdgcn_mfma_f32_16x16x32_bf16(af, bfr, acc[j], 0, 0, 0);
    }
  }
#pragma unroll
  for (int j = 0; j < 4; ++j) {
    int col = c0 + j * 16 + (lane & 15);
    float bb = bdt[col];
#pragma unroll
    for (int r = 0; r < 4; ++r) {
      int row = r0 + ((lane >> 4) << 2) + r;
      float v = acc[j][r] + bb;
      v = (v > 20.f) ? v : log1pf(__expf(v));
      dtf[(size_t)row * DINNER + col] = v;
    }
  }
}

// ---------------- scan pass A: per-chunk (prod dA, local h) ----------------
__global__ __launch_bounds__(256) void k_scanA(const float* __restrict__ dtf, const float* __restrict__ xsf,
                                               const float* __restrict__ xdbl, const float* __restrict__ A_log,
                                               float* __restrict__ Sp, float* __restrict__ Ss) {
  int gid = blockIdx.x * 256 + threadIdx.x;
  int c = gid & (DINNER - 1);
  int chunk = (gid >> 11) & (NC - 1);
  int b = gid >> 16;
  int t0 = b * LSEQ + chunk * CL;
  float a[16];
#pragma unroll
  for (int n = 0; n < 16; n += 4) {
    float4 al = reinterpret_cast<const float4*>(A_log + (size_t)c * 16)[n >> 2];
    a[n] = -__expf(al.x); a[n + 1] = -__expf(al.y); a[n + 2] = -__expf(al.z); a[n + 3] = -__expf(al.w);
  }
  float ap[16], h[16];
#pragma unroll
  for (int n = 0; n < 16; ++n) { ap[n] = 1.f; h[n] = 0.f; }
  for (int l = 0; l < CL; ++l) {
    int t = t0 + l;
    float dt = dtf[(size_t)t * DINNER + c];
    float xv = xsf[(size_t)t * DINNER + c];
    float dtx = dt * xv;
    const float4* bp = reinterpret_cast<const float4*>(xdbl + (size_t)t * NXD + DTRANK);
    float4 b0 = bp[0], b1 = bp[1], b2 = bp[2], b3 = bp[3];
    float bv[16] = { b0.x, b0.y, b0.z, b0.w, b1.x, b1.y, b1.z, b1.w,
                     b2.x, b2.y, b2.z, b2.w, b3.x, b3.y, b3.z, b3.w };
#pragma unroll
    for (int n = 0; n < 16; ++n) {
      float e = __expf(dt * a[n]);
      ap[n] *= e;
      h[n] = e * h[n] + dtx * bv[n];
    }
  }
  size_t base = ((size_t)(b * NC + chunk) * 16) * DINNER + c;
#pragma unroll
  for (int n = 0; n < 16; ++n) {
    Sp[base + (size_t)n * DINNER] = ap[n];
    Ss[base + (size_t)n * DINNER] = h[n];
  }
}

// ---------------- scan pass B: combine chunk summaries -> h_init per chunk ----------------
// one thread per (b, n, c): 65536 threads, serial only over the 32 chunks
__global__ __launch_bounds__(256) void k_scanB(const float* __restrict__ Sp, const float* __restrict__ Ss,
                                               float* __restrict__ Hi) {
  int gid = blockIdx.x * 256 + threadIdx.x;
  int c = gid & (DINNER - 1);
  int n = (gid >> 11) & 15;
  int b = gid >> 15;
  size_t idx = ((size_t)(b * NC) * 16 + n) * DINNER + c;
  const size_t stride = (size_t)16 * DINNER;
  float h = 0.f;
  for (int chunk = 0; chunk < NC; ++chunk) {
    Hi[idx] = h;
    h = Sp[idx] * h + Ss[idx];
    idx += stride;
  }
}

// ---------------- scan pass C: replay with h_init, fuse y + gate -> y bf16 ----------------
__global__ __launch_bounds__(256) void k_scanC(const float* __restrict__ dtf, const float* __restrict__ xsf,
                                               const float* __restrict__ xdbl, const float* __restrict__ A_log,
                                               const float* __restrict__ Hi, const float* __restrict__ Dp,
                                               const float* __restrict__ xz, bf16_t* __restrict__ yB) {
  int gid = blockIdx.x * 256 + threadIdx.x;
  int c = gid & (DINNER - 1);
  int chunk = (gid >> 11) & (NC - 1);
  int b = gid >> 16;
  int t0 = b * LSEQ + chunk * CL;
  float a[16];
#pragma unroll
  for (int n = 0; n < 16; n += 4) {
    float4 al = reinterpret_cast<const float4*>(A_log + (size_t)c * 16)[n >> 2];
    a[n] = -__expf(al.x); a[n + 1] = -__expf(al.y); a[n + 2] = -__expf(al.z); a[n + 3] = -__expf(al.w);
  }
  float h[16];
  size_t base = ((size_t)(b * NC + chunk) * 16) * DINNER + c;
#pragma unroll
  for (int n = 0; n < 16; ++n) h[n] = Hi[base + (size_t)n * DINNER];
  float dpc = Dp[c];
  for (int l = 0; l < CL; ++l) {
    int t = t0 + l;
    float dt = dtf[(size_t)t * DINNER + c];
    float xv = xsf[(size_t)t * DINNER + c];
    float dtx = dt * xv;
    const float4* bp = reinterpret_cast<const float4*>(xdbl + (size_t)t * NXD + DTRANK);
    float4 b0 = bp[0], b1 = bp[1], b2 = bp[2], b3 = bp[3];
    float bv[16] = { b0.x, b0.y, b0.z, b0.w, b1.x, b1.y, b1.z, b1.w,
                     b2.x, b2.y, b2.z, b2.w, b3.x, b3.y, b3.z, b3.w };
    const float4* cp = reinterpret_cast<const float4*>(xdbl + (size_t)t * NXD + DTRANK + 16);
    float4 c0 = cp[0], c1 = cp[1], c2 = cp[2], c3 = cp[3];
    float cv[16] = { c0.x, c0.y, c0.z, c0.w, c1.x, c1.y, c1.z, c1.w,
                     c2.x, c2.y, c2.z, c2.w, c3.x, c3.y, c3.z, c3.w };
    float y = 0.f;
#pragma unroll
    for (int n = 0; n < 16; ++n) {
      float e = __expf(dt * a[n]);
      h[n] = e * h[n] + dtx * bv[n];
      y += h[n] * cv[n];
    }
    y += dpc * xv;
    float zv = xz[(size_t)t * 4096 + DINNER + c];
    y *= zv / (1.f + __expf(-zv));
    yB[(size_t)t * DINNER + c] = (bf16_t)y;
  }
}

extern "C" void kernel_launch(void* const* d_in, const int* in_sizes, int n_in,
                              void* d_out, int out_size, void* d_ws, size_t ws_size,
                              hipStream_t stream) {
  (void)in_sizes; (void)n_in; (void)out_size; (void)ws_size;
  const float* x      = (const float*)d_in[0];
  const float* ln_w   = (const float*)d_in[1];
  const float* ln_b   = (const float*)d_in[2];
  const float* W_in   = (const float*)d_in[3];
  const float* conv_w = (const float*)d_in[4];
  const float* conv_b = (const float*)d_in[5];
  const float* W_x    = (const float*)d_in[6];
  const float* W_dt   = (const float*)d_in[7];
  const float* b_dt   = (const float*)d_in[8];
  const float* A_log  = (const float*)d_in[9];
  const float* Dp     = (const float*)d_in[10];
  const float* W_out  = (const float*)d_in[11];
  float* out = (float*)d_out;

  char* ws = (char*)d_ws;
  size_t off = 0;
  auto alloc = [&](size_t bytes) { void* p = ws + off; off += (bytes + 255) & ~255ull; return p; };
  bf16_t* wInB  = (bf16_t*)alloc((size_t)4096 * 1024 * 2);
  bf16_t* wXB   = (bf16_t*)alloc((size_t)96 * 2048 * 2);
  bf16_t* wDtB  = (bf16_t*)alloc((size_t)2048 * 64 * 2);
  bf16_t* wOutB = (bf16_t*)alloc((size_t)1024 * 2048 * 2);
  bf16_t* xnB   = (bf16_t*)alloc((size_t)NTOK * DMODEL * 2);
  float*  xz    = (float*)alloc((size_t)NTOK * 4096 * 4);
  float*  xsf   = (float*)alloc((size_t)NTOK * DINNER * 4);
  bf16_t* xsB   = (bf16_t*)alloc((size_t)NTOK * DINNER * 2);
  float*  xdbl  = (float*)alloc((size_t)NTOK * NXD * 4);
  float*  dtf   = (float*)alloc((size_t)NTOK * DINNER * 4);
  float*  Sp    = (float*)alloc((size_t)2 * NC * 16 * DINNER * 4);
  float*  Ss    = (float*)alloc((size_t)2 * NC * 16 * DINNER * 4);
  float*  Hi    = (float*)alloc((size_t)2 * NC * 16 * DINNER * 4);
  bf16_t* yB    = (bf16_t*)alloc((size_t)NTOK * DINNER * 2);

  // fused weight conversion (1 launch instead of 4)
  k_cvt4<<<(CVT_N3 + 255) / 256, 256, 0, stream>>>(W_in, W_x, W_dt, W_out, wInB, wXB, wDtB, wOutB);

  // layernorm
  k_ln<<<NTOK, 256, 0, stream>>>(x, ln_w, ln_b, xnB);

  // in_proj: xz[2048][4096]  (512 WGs)
  k_gemm<128, false><<<dim3(4096 / 128, NTOK / 128), 256, 0, stream>>>(xnB, wInB, xz, nullptr, 4096, 1024);

  // conv + silu
  k_conv<<<NTOK * DINNER / 256, 256, 0, stream>>>(xz, conv_w, conv_b, xsf, xsB);

  // x_proj (K-split across 4 waves)
  k_xproj<<<NTOK / 16, 256, 0, stream>>>(xsB, wXB, xdbl);

  // dt_proj + softplus
  k_dtproj<<<dim3(DINNER / 64, NTOK / 64), 256, 0, stream>>>(xdbl, wDtB, b_dt, dtf);

  // chunked scan
  k_scanA<<<2 * NC * DINNER / 256, 256, 0, stream>>>(dtf, xsf, xdbl, A_log, Sp, Ss);
  k_scanB<<<2 * 16 * DINNER / 256, 256, 0, stream>>>(Sp, Ss, Hi);
  k_scanC<<<2 * NC * DINNER / 256, 256, 0, stream>>>(dtf, xsf, xdbl, A_log, Hi, Dp, xz, yB);

  // out_proj + residual (BM=64 -> 256 WGs, full CU coverage)
  k_gemm<64, true><<<dim3(1024 / 128, NTOK / 64), 256, 0, stream>>>(yB, wOutB, out, x, 1024, 2048);
}

// Round 6
// 280.147 us; speedup vs baseline: 1.4452x; 1.1130x over previous
//
#include <hip/hip_runtime.h>

typedef __bf16 bf16_t;
typedef __bf16 bf16x8 __attribute__((ext_vector_type(8)));
typedef __bf16 bf16x4 __attribute__((ext_vector_type(4)));
typedef float f32x4 __attribute__((ext_vector_type(4)));
typedef unsigned int u32;

#define NTOK 2048   // B*L
#define LSEQ 1024
#define DMODEL 1024
#define DINNER 2048
#define NXD 96      // DT_RANK + 2*D_STATE
#define DTRANK 64
#define NC 64       // scan chunks per sequence
#define CL 16       // chunk length (NC*CL == LSEQ)

__device__ __forceinline__ void gload16(const void* g, void* l) {
  __builtin_amdgcn_global_load_lds((const __attribute__((address_space(1))) u32*)g,
                                   (__attribute__((address_space(3))) u32*)l, 16, 0, 0);
}

// ---------------- fused fp32 -> bf16 weight convert (4 arrays, 1 launch) ----------------
#define CVT_N0 1048576            // W_in  / 4
#define CVT_N1 (CVT_N0 + 49152)   // + W_x / 4
#define CVT_N2 (CVT_N1 + 32768)   // + W_dt / 4
#define CVT_N3 (CVT_N2 + 524288)  // + W_out / 4
__global__ __launch_bounds__(256) void k_cvt4(const float* __restrict__ a0, const float* __restrict__ a1,
                                              const float* __restrict__ a2, const float* __restrict__ a3,
                                              bf16_t* __restrict__ o0, bf16_t* __restrict__ o1,
                                              bf16_t* __restrict__ o2, bf16_t* __restrict__ o3) {
  int i = blockIdx.x * 256 + threadIdx.x;
  const float* src; bf16_t* dst; int idx;
  if (i < CVT_N0)      { src = a0; dst = o0; idx = i; }
  else if (i < CVT_N1) { src = a1; dst = o1; idx = i - CVT_N0; }
  else if (i < CVT_N2) { src = a2; dst = o2; idx = i - CVT_N1; }
  else if (i < CVT_N3) { src = a3; dst = o3; idx = i - CVT_N2; }
  else return;
  float4 v = reinterpret_cast<const float4*>(src)[idx];
  bf16x4 o = { (bf16_t)v.x, (bf16_t)v.y, (bf16_t)v.z, (bf16_t)v.w };
  reinterpret_cast<bf16x4*>(dst)[idx] = o;
}

// ---------------- LayerNorm -> bf16 ----------------
__global__ __launch_bounds__(256) void k_ln(const float* __restrict__ x, const float* __restrict__ w,
                                            const float* __restrict__ b, bf16_t* __restrict__ xn) {
  const int row = blockIdx.x;
  const int tid = threadIdx.x;
  float4 v = reinterpret_cast<const float4*>(x + (size_t)row * DMODEL)[tid];
  float s = v.x + v.y + v.z + v.w;
  float q = v.x*v.x + v.y*v.y + v.z*v.z + v.w*v.w;
#pragma unroll
  for (int o = 32; o > 0; o >>= 1) { s += __shfl_down(s, o); q += __shfl_down(q, o); }
  __shared__ float sh[8];
  int wv = tid >> 6;
  if ((tid & 63) == 0) { sh[wv] = s; sh[4 + wv] = q; }
  __syncthreads();
  if (tid == 0) {
    sh[0] = sh[0] + sh[1] + sh[2] + sh[3];
    sh[4] = sh[4] + sh[5] + sh[6] + sh[7];
  }
  __syncthreads();
  float mu = sh[0] * (1.f / DMODEL);
  float var = sh[4] * (1.f / DMODEL) - mu * mu;
  float rs = rsqrtf(var + 1e-5f);
  float4 w4 = reinterpret_cast<const float4*>(w)[tid];
  float4 b4 = reinterpret_cast<const float4*>(b)[tid];
  bf16x4 o = { (bf16_t)((v.x - mu) * rs * w4.x + b4.x),
               (bf16_t)((v.y - mu) * rs * w4.y + b4.y),
               (bf16_t)((v.z - mu) * rs * w4.z + b4.z),
               (bf16_t)((v.w - mu) * rs * w4.w + b4.w) };
  reinterpret_cast<bf16x4*>(xn + (size_t)row * DMODEL)[tid] = o;
}

// ---------------- BMx128 MFMA GEMM, C = A(MxK) * Bt(NxK)^T [+ resid], XCD-swizzled ----------------
// OUTBF: store bf16 instead of fp32
template <int BM, bool RESID, bool OUTBF>
__global__ __launch_bounds__(256) void k_gemm(const bf16_t* __restrict__ A, const bf16_t* __restrict__ Bt,
                                              void* __restrict__ Cout, const float* __restrict__ R,
                                              int N, int K) {
  constexpr int BN = 128;
  constexpr int MR = BM / 32;
  constexpr int NCHUNK = (BM + BN) * 4;
  constexpr int ITER = NCHUNK / 256;
  __shared__ bf16_t As[BM * 32];
  __shared__ bf16_t Bs[BN * 32];
  const int tid = threadIdx.x;
  const int w = tid >> 6, lane = tid & 63;

  // XCD-aware swizzle (nwg % 8 == 0 for all our launches)
  const int nbx = gridDim.x;
  int nwg = gridDim.x * gridDim.y;
  int orig = blockIdx.y * gridDim.x + blockIdx.x;
  int cpx = nwg >> 3;
  int swz = (orig & 7) * cpx + (orig >> 3);
  int bx = swz % nbx, by = swz / nbx;
  const int brow = by * BM, bcol = bx * BN;
  const int wr = (w >> 1) * (BM / 2), wc = (w & 1) * 64;

  const bf16_t* gsrc[ITER];
  bf16_t* lbase[ITER];
#pragma unroll
  for (int i = 0; i < ITER; ++i) {
    int p0 = i * 256 + w * 64;
    int p = p0 + lane;
    if (p0 < BM * 4) {
      gsrc[i] = A + (size_t)(brow + (p >> 2)) * K + (p & 3) * 8;
      lbase[i] = &As[p0 * 8];
    } else {
      int q = p - BM * 4, q0 = p0 - BM * 4;
      gsrc[i] = Bt + (size_t)(bcol + (q >> 2)) * K + (q & 3) * 8;
      lbase[i] = &Bs[q0 * 8];
    }
  }

  f32x4 acc[MR][4] = {};
  for (int kk = 0; kk < K; kk += 32) {
    __syncthreads();
#pragma unroll
    for (int i = 0; i < ITER; ++i) gload16(gsrc[i] + kk, lbase[i]);
    __syncthreads();
    bf16x8 af[MR], bfr[4];
#pragma unroll
    for (int m = 0; m < MR; ++m)
      af[m] = *reinterpret_cast<const bf16x8*>(&As[(wr + m * 16 + (lane & 15)) * 32 + (lane >> 4) * 8]);
#pragma unroll
    for (int n = 0; n < 4; ++n)
      bfr[n] = *reinterpret_cast<const bf16x8*>(&Bs[(wc + n * 16 + (lane & 15)) * 32 + (lane >> 4) * 8]);
#pragma unroll
    for (int m = 0; m < MR; ++m)
#pragma unroll
      for (int n = 0; n < 4; ++n)
        acc[m][n] = __builtin_amdgcn_mfma_f32_16x16x32_bf16(af[m], bfr[n], acc[m][n], 0, 0, 0);
  }

#pragma unroll
  for (int m = 0; m < MR; ++m) {
#pragma unroll
    for (int n = 0; n < 4; ++n) {
      int col = bcol + wc + n * 16 + (lane & 15);
#pragma unroll
      for (int r = 0; r < 4; ++r) {
        int row = brow + wr + m * 16 + ((lane >> 4) << 2) + r;
        float v = acc[m][n][r];
        if (RESID) v += R[(size_t)row * N + col];
        if (OUTBF) ((bf16_t*)Cout)[(size_t)row * N + col] = (bf16_t)v;
        else       ((float*)Cout)[(size_t)row * N + col] = v;
      }
    }
  }
}

// ---------------- depthwise causal conv1d + SiLU (bf16 xz input) ----------------
__global__ __launch_bounds__(256) void k_conv(const bf16_t* __restrict__ xz, const float* __restrict__ cw,
                                              const float* __restrict__ cb, float* __restrict__ xsf,
                                              bf16_t* __restrict__ xsB) {
  int gid = blockIdx.x * 256 + threadIdx.x;
  int c = gid & (DINNER - 1);
  int t = gid >> 11;
  int l = t & (LSEQ - 1);
  float4 w4 = reinterpret_cast<const float4*>(cw)[c];
  float wk[4] = { w4.x, w4.y, w4.z, w4.w };
  float v = cb[c];
#pragma unroll
  for (int k = 0; k < 4; ++k) {
    int ll = l + k - 3;
    if (ll >= 0) v += wk[k] * (float)xz[(size_t)(t + k - 3) * 4096 + c];
  }
  float sv = v / (1.f + __expf(-v));
  xsf[(size_t)t * DINNER + c] = sv;
  xsB[(size_t)t * DINNER + c] = (bf16_t)sv;
}

// ---------------- x_proj: xdbl[2048][96] = xs(bf16) @ W_x^T, K split across 4 waves ----------------
__global__ __launch_bounds__(256) void k_xproj(const bf16_t* __restrict__ A, const bf16_t* __restrict__ Bt,
                                               float* __restrict__ C) {
  __shared__ f32x4 red[4][6][64];
  int tid = threadIdx.x, w = tid >> 6, lane = tid & 63;
  int r0 = blockIdx.x * 16;
  int arow = r0 + (lane & 15);
  int kof = (lane >> 4) * 8;
  f32x4 acc[6] = {};
  for (int k = w * 512; k < (w + 1) * 512; k += 32) {
    bf16x8 af = *reinterpret_cast<const bf16x8*>(A + (size_t)arow * DINNER + k + kof);
#pragma unroll
    for (int j = 0; j < 6; ++j) {
      bf16x8 bfr = *reinterpret_cast<const bf16x8*>(Bt + (size_t)(j * 16 + (lane & 15)) * DINNER + k + kof);
      acc[j] = __builtin_amdgcn_mfma_f32_16x16x32_bf16(af, bfr, acc[j], 0, 0, 0);
    }
  }
#pragma unroll
  for (int j = 0; j < 6; ++j) red[w][j][lane] = acc[j];
  __syncthreads();
  for (int item = tid; item < 384; item += 256) {
    int j = item >> 6, li = item & 63;
    f32x4 s = red[0][j][li];
#pragma unroll
    for (int ww = 1; ww < 4; ++ww) s += red[ww][j][li];
    int col = j * 16 + (li & 15);
    int rowb = r0 + ((li >> 4) << 2);
#pragma unroll
    for (int r = 0; r < 4; ++r) C[(size_t)(rowb + r) * NXD + col] = s[r];
  }
}

// ---------------- dt_proj (K=64) + softplus ----------------
__global__ __launch_bounds__(256) void k_dtproj(const float* __restrict__ xdbl, const bf16_t* __restrict__ Wdt,
                                                const float* __restrict__ bdt, float* __restrict__ dtf) {
  int tid = threadIdx.x, w = tid >> 6, lane = tid & 63;
  int r0 = blockIdx.y * 64 + w * 16;
  int c0 = blockIdx.x * 64;
  int arow = r0 + (lane & 15);
  int kof = (lane >> 4) * 8;
  f32x4 acc[4] = {};
#pragma unroll
  for (int ks = 0; ks < 2; ++ks) {
    int k = ks * 32;
    const float* ap = xdbl + (size_t)arow * NXD + k + kof;
    float4 a0 = *reinterpret_cast<const float4*>(ap);
    float4 a1 = *reinterpret_cast<const float4*>(ap + 4);
    bf16x8 af = { (bf16_t)a0.x, (bf16_t)a0.y, (bf16_t)a0.z, (bf16_t)a0.w,
                  (bf16_t)a1.x, (bf16_t)a1.y, (bf16_t)a1.z, (bf16_t)a1.w };
#pragma unroll
    for (int j = 0; j < 4; ++j) {
      bf16x8 bfr = *reinterpret_cast<const bf16x8*>(Wdt + (size_t)(c0 + j * 16 + (lane & 15)) * DTRANK + k + kof);
      acc[j] = __builtin_amdgcn_mfma_f32_16x16x32_bf16(af, bfr, acc[j], 0, 0, 0);
    }
  }
#pragma unroll
  for (int j = 0; j < 4; ++j) {
    int col = c0 + j * 16 + (lane & 15);
    float bb = bdt[col];
#pragma unroll
    for (int r = 0; r < 4; ++r) {
      int row = r0 + ((lane >> 4) << 2) + r;
      float v = acc[j][r] + bb;
      v = (v > 20.f) ? v : log1pf(__expf(v));
      dtf[(size_t)row * DINNER + col] = v;
    }
  }
}

// ---------------- scan pass A: per-chunk (prod dA, local h) ----------------
__global__ __launch_bounds__(256) void k_scanA(const float* __restrict__ dtf, const float* __restrict__ xsf,
                                               const float* __restrict__ xdbl, const float* __restrict__ A_log,
                                               float* __restrict__ Sp, float* __restrict__ Ss) {
  int gid = blockIdx.x * 256 + threadIdx.x;
  int c = gid & (DINNER - 1);
  int chunk = (gid >> 11) & (NC - 1);
  int b = gid >> 17;
  int t0 = b * LSEQ + chunk * CL;
  float a[16];
#pragma unroll
  for (int n = 0; n < 16; n += 4) {
    float4 al = reinterpret_cast<const float4*>(A_log + (size_t)c * 16)[n >> 2];
    a[n] = -__expf(al.x); a[n + 1] = -__expf(al.y); a[n + 2] = -__expf(al.z); a[n + 3] = -__expf(al.w);
  }
  float ap[16], h[16];
#pragma unroll
  for (int n = 0; n < 16; ++n) { ap[n] = 1.f; h[n] = 0.f; }
#pragma unroll 4
  for (int l = 0; l < CL; ++l) {
    int t = t0 + l;
    float dt = dtf[(size_t)t * DINNER + c];
    float xv = xsf[(size_t)t * DINNER + c];
    float dtx = dt * xv;
    const float4* bp = reinterpret_cast<const float4*>(xdbl + (size_t)t * NXD + DTRANK);
    float4 b0 = bp[0], b1 = bp[1], b2 = bp[2], b3 = bp[3];
    float bv[16] = { b0.x, b0.y, b0.z, b0.w, b1.x, b1.y, b1.z, b1.w,
                     b2.x, b2.y, b2.z, b2.w, b3.x, b3.y, b3.z, b3.w };
#pragma unroll
    for (int n = 0; n < 16; ++n) {
      float e = __expf(dt * a[n]);
      ap[n] *= e;
      h[n] = e * h[n] + dtx * bv[n];
    }
  }
  size_t base = ((size_t)(b * NC + chunk) * 16) * DINNER + c;
#pragma unroll
  for (int n = 0; n < 16; ++n) {
    Sp[base + (size_t)n * DINNER] = ap[n];
    Ss[base + (size_t)n * DINNER] = h[n];
  }
}

// ---------------- scan pass B: combine chunk summaries -> h_init per chunk ----------------
__global__ __launch_bounds__(256) void k_scanB(const float* __restrict__ Sp, const float* __restrict__ Ss,
                                               float* __restrict__ Hi) {
  int gid = blockIdx.x * 256 + threadIdx.x;
  int c = gid & (DINNER - 1);
  int n = (gid >> 11) & 15;
  int b = gid >> 15;
  size_t idx = ((size_t)(b * NC) * 16 + n) * DINNER + c;
  const size_t stride = (size_t)16 * DINNER;
  float h = 0.f;
#pragma unroll 4
  for (int chunk = 0; chunk < NC; ++chunk) {
    Hi[idx] = h;
    h = Sp[idx] * h + Ss[idx];
    idx += stride;
  }
}

// ---------------- scan pass C: replay with h_init, fuse y + gate -> y bf16 ----------------
__global__ __launch_bounds__(256) void k_scanC(const float* __restrict__ dtf, const float* __restrict__ xsf,
                                               const float* __restrict__ xdbl, const float* __restrict__ A_log,
                                               const float* __restrict__ Hi, const float* __restrict__ Dp,
                                               const bf16_t* __restrict__ xz, bf16_t* __restrict__ yB) {
  int gid = blockIdx.x * 256 + threadIdx.x;
  int c = gid & (DINNER - 1);
  int chunk = (gid >> 11) & (NC - 1);
  int b = gid >> 17;
  int t0 = b * LSEQ + chunk * CL;
  float a[16];
#pragma unroll
  for (int n = 0; n < 16; n += 4) {
    float4 al = reinterpret_cast<const float4*>(A_log + (size_t)c * 16)[n >> 2];
    a[n] = -__expf(al.x); a[n + 1] = -__expf(al.y); a[n + 2] = -__expf(al.z); a[n + 3] = -__expf(al.w);
  }
  float h[16];
  size_t base = ((size_t)(b * NC + chunk) * 16) * DINNER + c;
#pragma unroll
  for (int n = 0; n < 16; ++n) h[n] = Hi[base + (size_t)n * DINNER];
  float dpc = Dp[c];
#pragma unroll 4
  for (int l = 0; l < CL; ++l) {
    int t = t0 + l;
    float dt = dtf[(size_t)t * DINNER + c];
    float xv = xsf[(size_t)t * DINNER + c];
    float zv = (float)xz[(size_t)t * 4096 + DINNER + c];
    float dtx = dt * xv;
    const float4* bp = reinterpret_cast<const float4*>(xdbl + (size_t)t * NXD + DTRANK);
    float4 b0 = bp[0], b1 = bp[1], b2 = bp[2], b3 = bp[3];
    float bv[16] = { b0.x, b0.y, b0.z, b0.w, b1.x, b1.y, b1.z, b1.w,
                     b2.x, b2.y, b2.z, b2.w, b3.x, b3.y, b3.z, b3.w };
    const float4* cp = reinterpret_cast<const float4*>(xdbl + (size_t)t * NXD + DTRANK + 16);
    float4 c0 = cp[0], c1 = cp[1], c2 = cp[2], c3 = cp[3];
    float cv[16] = { c0.x, c0.y, c0.z, c0.w, c1.x, c1.y, c1.z, c1.w,
                     c2.x, c2.y, c2.z, c2.w, c3.x, c3.y, c3.z, c3.w };
    float y = 0.f;
#pragma unroll
    for (int n = 0; n < 16; ++n) {
      float e = __expf(dt * a[n]);
      h[n] = e * h[n] + dtx * bv[n];
      y += h[n] * cv[n];
    }
    y += dpc * xv;
    y *= zv / (1.f + __expf(-zv));
    yB[(size_t)t * DINNER + c] = (bf16_t)y;
  }
}

extern "C" void kernel_launch(void* const* d_in, const int* in_sizes, int n_in,
                              void* d_out, int out_size, void* d_ws, size_t ws_size,
                              hipStream_t stream) {
  (void)in_sizes; (void)n_in; (void)out_size; (void)ws_size;
  const float* x      = (const float*)d_in[0];
  const float* ln_w   = (const float*)d_in[1];
  const float* ln_b   = (const float*)d_in[2];
  const float* W_in   = (const float*)d_in[3];
  const float* conv_w = (const float*)d_in[4];
  const float* conv_b = (const float*)d_in[5];
  const float* W_x    = (const float*)d_in[6];
  const float* W_dt   = (const float*)d_in[7];
  const float* b_dt   = (const float*)d_in[8];
  const float* A_log  = (const float*)d_in[9];
  const float* Dp     = (const float*)d_in[10];
  const float* W_out  = (const float*)d_in[11];
  float* out = (float*)d_out;

  char* ws = (char*)d_ws;
  size_t off = 0;
  auto alloc = [&](size_t bytes) { void* p = ws + off; off += (bytes + 255) & ~255ull; return p; };
  bf16_t* wInB  = (bf16_t*)alloc((size_t)4096 * 1024 * 2);
  bf16_t* wXB   = (bf16_t*)alloc((size_t)96 * 2048 * 2);
  bf16_t* wDtB  = (bf16_t*)alloc((size_t)2048 * 64 * 2);
  bf16_t* wOutB = (bf16_t*)alloc((size_t)1024 * 2048 * 2);
  bf16_t* xnB   = (bf16_t*)alloc((size_t)NTOK * DMODEL * 2);
  bf16_t* xzB   = (bf16_t*)alloc((size_t)NTOK * 4096 * 2);
  float*  xsf   = (float*)alloc((size_t)NTOK * DINNER * 4);
  bf16_t* xsB   = (bf16_t*)alloc((size_t)NTOK * DINNER * 2);
  float*  xdbl  = (float*)alloc((size_t)NTOK * NXD * 4);
  float*  dtf   = (float*)alloc((size_t)NTOK * DINNER * 4);
  float*  Sp    = (float*)alloc((size_t)2 * NC * 16 * DINNER * 4);
  float*  Ss    = (float*)alloc((size_t)2 * NC * 16 * DINNER * 4);
  float*  Hi    = (float*)alloc((size_t)2 * NC * 16 * DINNER * 4);
  bf16_t* yB    = (bf16_t*)alloc((size_t)NTOK * DINNER * 2);

  // fused weight conversion
  k_cvt4<<<(CVT_N3 + 255) / 256, 256, 0, stream>>>(W_in, W_x, W_dt, W_out, wInB, wXB, wDtB, wOutB);

  // layernorm
  k_ln<<<NTOK, 256, 0, stream>>>(x, ln_w, ln_b, xnB);

  // in_proj: xz[2048][4096] bf16
  k_gemm<128, false, true><<<dim3(4096 / 128, NTOK / 128), 256, 0, stream>>>(xnB, wInB, xzB, nullptr, 4096, 1024);

  // conv + silu
  k_conv<<<NTOK * DINNER / 256, 256, 0, stream>>>(xzB, conv_w, conv_b, xsf, xsB);

  // x_proj (K-split across 4 waves)
  k_xproj<<<NTOK / 16, 256, 0, stream>>>(xsB, wXB, xdbl);

  // dt_proj + softplus
  k_dtproj<<<dim3(DINNER / 64, NTOK / 64), 256, 0, stream>>>(xdbl, wDtB, b_dt, dtf);

  // chunked scan (NC=64 -> 1024 blocks for A/C)
  k_scanA<<<2 * NC * DINNER / 256, 256, 0, stream>>>(dtf, xsf, xdbl, A_log, Sp, Ss);
  k_scanB<<<2 * 16 * DINNER / 256, 256, 0, stream>>>(Sp, Ss, Hi);
  k_scanC<<<2 * NC * DINNER / 256, 256, 0, stream>>>(dtf, xsf, xdbl, A_log, Hi, Dp, xzB, yB);

  // out_proj + residual (BM=64 -> 256 WGs)
  k_gemm<64, true, false><<<dim3(1024 / 128, NTOK / 64), 256, 0, stream>>>(yB, wOutB, out, x, 1024, 2048);
}

// Round 10
// 271.476 us; speedup vs baseline: 1.4913x; 1.0319x over previous
//
#include <hip/hip_runtime.h>

typedef __bf16 bf16_t;
typedef __bf16 bf16x8 __attribute__((ext_vector_type(8)));
typedef __bf16 bf16x4 __attribute__((ext_vector_type(4)));
typedef float f32x4 __attribute__((ext_vector_type(4)));
typedef unsigned int u32;

#define NTOK 2048   // B*L
#define LSEQ 1024
#define DMODEL 1024
#define DINNER 2048
#define NXD 96      // DT_RANK + 2*D_STATE
#define DTRANK 64
#define NC 64       // scan chunks per sequence
#define CL 16       // chunk length (NC*CL == LSEQ)

__device__ __forceinline__ void gload16(const void* g, void* l) {
  __builtin_amdgcn_global_load_lds((const __attribute__((address_space(1))) u32*)g,
                                   (__attribute__((address_space(3))) u32*)l, 16, 0, 0);
}

// ---------------- fused fp32 -> bf16 weight convert (4 arrays, 1 launch) ----------------
#define CVT_N0 1048576            // W_in  / 4
#define CVT_N1 (CVT_N0 + 49152)   // + W_x / 4
#define CVT_N2 (CVT_N1 + 32768)   // + W_dt / 4
#define CVT_N3 (CVT_N2 + 524288)  // + W_out / 4
__global__ __launch_bounds__(256) void k_cvt4(const float* __restrict__ a0, const float* __restrict__ a1,
                                              const float* __restrict__ a2, const float* __restrict__ a3,
                                              bf16_t* __restrict__ o0, bf16_t* __restrict__ o1,
                                              bf16_t* __restrict__ o2, bf16_t* __restrict__ o3) {
  int i = blockIdx.x * 256 + threadIdx.x;
  const float* src; bf16_t* dst; int idx;
  if (i < CVT_N0)      { src = a0; dst = o0; idx = i; }
  else if (i < CVT_N1) { src = a1; dst = o1; idx = i - CVT_N0; }
  else if (i < CVT_N2) { src = a2; dst = o2; idx = i - CVT_N1; }
  else if (i < CVT_N3) { src = a3; dst = o3; idx = i - CVT_N2; }
  else return;
  float4 v = reinterpret_cast<const float4*>(src)[idx];
  bf16x4 o = { (bf16_t)v.x, (bf16_t)v.y, (bf16_t)v.z, (bf16_t)v.w };
  reinterpret_cast<bf16x4*>(dst)[idx] = o;
}

// ---------------- LayerNorm -> bf16 ----------------
__global__ __launch_bounds__(256) void k_ln(const float* __restrict__ x, const float* __restrict__ w,
                                            const float* __restrict__ b, bf16_t* __restrict__ xn) {
  const int row = blockIdx.x;
  const int tid = threadIdx.x;
  float4 v = reinterpret_cast<const float4*>(x + (size_t)row * DMODEL)[tid];
  float s = v.x + v.y + v.z + v.w;
  float q = v.x*v.x + v.y*v.y + v.z*v.z + v.w*v.w;
#pragma unroll
  for (int o = 32; o > 0; o >>= 1) { s += __shfl_down(s, o); q += __shfl_down(q, o); }
  __shared__ float sh[8];
  int wv = tid >> 6;
  if ((tid & 63) == 0) { sh[wv] = s; sh[4 + wv] = q; }
  __syncthreads();
  if (tid == 0) {
    sh[0] = sh[0] + sh[1] + sh[2] + sh[3];
    sh[4] = sh[4] + sh[5] + sh[6] + sh[7];
  }
  __syncthreads();
  float mu = sh[0] * (1.f / DMODEL);
  float var = sh[4] * (1.f / DMODEL) - mu * mu;
  float rs = rsqrtf(var + 1e-5f);
  float4 w4 = reinterpret_cast<const float4*>(w)[tid];
  float4 b4 = reinterpret_cast<const float4*>(b)[tid];
  bf16x4 o = { (bf16_t)((v.x - mu) * rs * w4.x + b4.x),
               (bf16_t)((v.y - mu) * rs * w4.y + b4.y),
               (bf16_t)((v.z - mu) * rs * w4.z + b4.z),
               (bf16_t)((v.w - mu) * rs * w4.w + b4.w) };
  reinterpret_cast<bf16x4*>(xn + (size_t)row * DMODEL)[tid] = o;
}

// LDS slot swizzle: slot' = slot ^ ((row>>2)&3). Applied to global SOURCE (staging)
// and ds_read side; LDS dest stays linear (global_load_lds constraint, rule #21).

// ---------------- BMx128 MFMA GEMM, C = A(MxK) * Bt(NxK)^T [+ resid], XCD-swizzled ----------------
template <int BM, bool RESID, bool OUTBF>
__global__ __launch_bounds__(256) void k_gemm(const bf16_t* __restrict__ A, const bf16_t* __restrict__ Bt,
                                              void* __restrict__ Cout, const float* __restrict__ R,
                                              int N, int K) {
  constexpr int BN = 128;
  constexpr int MR = BM / 32;
  constexpr int NCHUNK = (BM + BN) * 4;
  constexpr int ITER = NCHUNK / 256;
  __shared__ bf16_t As[BM * 32];
  __shared__ bf16_t Bs[BN * 32];
  const int tid = threadIdx.x;
  const int w = tid >> 6, lane = tid & 63;

  // XCD-aware swizzle (nwg % 8 == 0 for all our launches)
  const int nbx = gridDim.x;
  int nwg = gridDim.x * gridDim.y;
  int orig = blockIdx.y * gridDim.x + blockIdx.x;
  int cpx = nwg >> 3;
  int swz = (orig & 7) * cpx + (orig >> 3);
  int bx = swz % nbx, by = swz / nbx;
  const int brow = by * BM, bcol = bx * BN;
  const int wr = (w >> 1) * (BM / 2), wc = (w & 1) * 64;

  const bf16_t* gsrc[ITER];
  bf16_t* lbase[ITER];
#pragma unroll
  for (int i = 0; i < ITER; ++i) {
    int p0 = i * 256 + w * 64;
    int p = p0 + lane;
    if (p0 < BM * 4) {
      int r = p >> 2, s = (p & 3) ^ ((r >> 2) & 3);
      gsrc[i] = A + (size_t)(brow + r) * K + s * 8;
      lbase[i] = &As[p0 * 8];
    } else {
      int q = p - BM * 4;
      int r = q >> 2, s = (q & 3) ^ ((r >> 2) & 3);
      gsrc[i] = Bt + (size_t)(bcol + r) * K + s * 8;
      lbase[i] = &Bs[(p0 - BM * 4) * 8];
    }
  }

  f32x4 acc[MR][4] = {};
  for (int kk = 0; kk < K; kk += 32) {
    __syncthreads();
#pragma unroll
    for (int i = 0; i < ITER; ++i) gload16(gsrc[i] + kk, lbase[i]);
    __syncthreads();
    bf16x8 af[MR], bfr[4];
#pragma unroll
    for (int m = 0; m < MR; ++m) {
      int rr = wr + m * 16 + (lane & 15);
      af[m] = *reinterpret_cast<const bf16x8*>(&As[rr * 32 + (((lane >> 4) ^ ((rr >> 2) & 3)) << 3)]);
    }
#pragma unroll
    for (int n = 0; n < 4; ++n) {
      int rc = wc + n * 16 + (lane & 15);
      bfr[n] = *reinterpret_cast<const bf16x8*>(&Bs[rc * 32 + (((lane >> 4) ^ ((rc >> 2) & 3)) << 3)]);
    }
#pragma unroll
    for (int m = 0; m < MR; ++m)
#pragma unroll
      for (int n = 0; n < 4; ++n)
        acc[m][n] = __builtin_amdgcn_mfma_f32_16x16x32_bf16(af[m], bfr[n], acc[m][n], 0, 0, 0);
  }

#pragma unroll
  for (int m = 0; m < MR; ++m) {
#pragma unroll
    for (int n = 0; n < 4; ++n) {
      int col = bcol + wc + n * 16 + (lane & 15);
#pragma unroll
      for (int r = 0; r < 4; ++r) {
        int row = brow + wr + m * 16 + ((lane >> 4) << 2) + r;
        float v = acc[m][n][r];
        if (RESID) v += R[(size_t)row * N + col];
        if (OUTBF) ((bf16_t*)Cout)[(size_t)row * N + col] = (bf16_t)v;
        else       ((float*)Cout)[(size_t)row * N + col] = v;
      }
    }
  }
}

// ---------------- out_proj split-K GEMM: P[split] = yB * W_out^T over K-slice ----------------
// grid dim3(8, 64): byf = (rowblk<<2)|split ; 512 WGs = 2 blocks/CU
__global__ __launch_bounds__(256) void k_gemmsk(const bf16_t* __restrict__ A, const bf16_t* __restrict__ Bt,
                                                float* __restrict__ P) {
  constexpr int BM = 128, BN = 128, K = 2048, N = 1024, KSP = 512;
  __shared__ bf16_t As[BM * 32];
  __shared__ bf16_t Bs[BN * 32];
  const int tid = threadIdx.x, w = tid >> 6, lane = tid & 63;
  const int nbx = gridDim.x;
  int nwg = gridDim.x * gridDim.y;
  int orig = blockIdx.y * gridDim.x + blockIdx.x;
  int cpx = nwg >> 3;
  int swz = (orig & 7) * cpx + (orig >> 3);
  int bx = swz % nbx, byf = swz / nbx;
  const int split = byf & 3, by = byf >> 2;
  const int brow = by * BM, bcol = bx * BN;
  const int wr = (w >> 1) * 64, wc = (w & 1) * 64;
  const int k0 = split * KSP;

  const bf16_t* gsrc[4];
  bf16_t* lbase[4];
#pragma unroll
  for (int i = 0; i < 4; ++i) {
    int p0 = i * 256 + w * 64;
    int p = p0 + lane;
    if (p0 < BM * 4) {
      int r = p >> 2, s = (p & 3) ^ ((r >> 2) & 3);
      gsrc[i] = A + (size_t)(brow + r) * K + s * 8;
      lbase[i] = &As[p0 * 8];
    } else {
      int q = p - BM * 4;
      int r = q >> 2, s = (q & 3) ^ ((r >> 2) & 3);
      gsrc[i] = Bt + (size_t)(bcol + r) * K + s * 8;
      lbase[i] = &Bs[(p0 - BM * 4) * 8];
    }
  }

  f32x4 acc[4][4] = {};
  for (int kk = k0; kk < k0 + KSP; kk += 32) {
    __syncthreads();
#pragma unroll
    for (int i = 0; i < 4; ++i) gload16(gsrc[i] + kk, lbase[i]);
    __syncthreads();
    bf16x8 af[4], bfr[4];
#pragma unroll
    for (int m = 0; m < 4; ++m) {
      int rr = wr + m * 16 + (lane & 15);
      af[m] = *reinterpret_cast<const bf16x8*>(&As[rr * 32 + (((lane >> 4) ^ ((rr >> 2) & 3)) << 3)]);
    }
#pragma unroll
    for (int n = 0; n < 4; ++n) {
      int rc = wc + n * 16 + (lane & 15);
      bfr[n] = *reinterpret_cast<const bf16x8*>(&Bs[rc * 32 + (((lane >> 4) ^ ((rc >> 2) & 3)) << 3)]);
    }
#pragma unroll
    for (int m = 0; m < 4; ++m)
#pragma unroll
      for (int n = 0; n < 4; ++n)
        acc[m][n] = __builtin_amdgcn_mfma_f32_16x16x32_bf16(af[m], bfr[n], acc[m][n], 0, 0, 0);
  }

  float* Pp = P + (size_t)split * ((size_t)NTOK * N);
#pragma unroll
  for (int m = 0; m < 4; ++m)
#pragma unroll
    for (int n = 0; n < 4; ++n) {
      int col = bcol + wc + n * 16 + (lane & 15);
#pragma unroll
      for (int r = 0; r < 4; ++r) {
        int row = brow + wr + m * 16 + ((lane >> 4) << 2) + r;
        Pp[(size_t)row * N + col] = acc[m][n][r];
      }
    }
}

// ---------------- split-K reduce + residual ----------------
__global__ __launch_bounds__(256) void k_red(const float* __restrict__ P, const float* __restrict__ x,
                                             float* __restrict__ out) {
  int i = blockIdx.x * 256 + threadIdx.x;   // float4 index, 2048*1024/4 total
  constexpr size_t S = (size_t)NTOK * 1024 / 4;
  float4 a = reinterpret_cast<const float4*>(P)[i];
  float4 b = reinterpret_cast<const float4*>(P)[i + S];
  float4 c = reinterpret_cast<const float4*>(P)[i + 2 * S];
  float4 d = reinterpret_cast<const float4*>(P)[i + 3 * S];
  float4 xv = reinterpret_cast<const float4*>(x)[i];
  float4 o = { a.x + b.x + c.x + d.x + xv.x,
               a.y + b.y + c.y + d.y + xv.y,
               a.z + b.z + c.z + d.z + xv.z,
               a.w + b.w + c.w + d.w + xv.w };
  reinterpret_cast<float4*>(out)[i] = o;
}

// ---------------- depthwise causal conv1d + SiLU (bf16 xz input) ----------------
__global__ __launch_bounds__(256) void k_conv(const bf16_t* __restrict__ xz, const float* __restrict__ cw,
                                              const float* __restrict__ cb, float* __restrict__ xsf,
                                              bf16_t* __restrict__ xsB) {
  int gid = blockIdx.x * 256 + threadIdx.x;
  int c = gid & (DINNER - 1);
  int t = gid >> 11;
  int l = t & (LSEQ - 1);
  float4 w4 = reinterpret_cast<const float4*>(cw)[c];
  float wk[4] = { w4.x, w4.y, w4.z, w4.w };
  float v = cb[c];
#pragma unroll
  for (int k = 0; k < 4; ++k) {
    int ll = l + k - 3;
    if (ll >= 0) v += wk[k] * (float)xz[(size_t)(t + k - 3) * 4096 + c];
  }
  float sv = v / (1.f + __expf(-v));
  xsf[(size_t)t * DINNER + c] = sv;
  xsB[(size_t)t * DINNER + c] = (bf16_t)sv;
}

// ---------------- x_proj: xdbl[2048][96] = xs(bf16) @ W_x^T, K split across 4 waves ----------------
__global__ __launch_bounds__(256) void k_xproj(const bf16_t* __restrict__ A, const bf16_t* __restrict__ Bt,
                                               float* __restrict__ C) {
  __shared__ f32x4 red[4][6][64];
  int tid = threadIdx.x, w = tid >> 6, lane = tid & 63;
  int r0 = blockIdx.x * 16;
  int arow = r0 + (lane & 15);
  int kof = (lane >> 4) * 8;
  f32x4 acc[6] = {};
  for (int k = w * 512; k < (w + 1) * 512; k += 32) {
    bf16x8 af = *reinterpret_cast<const bf16x8*>(A + (size_t)arow * DINNER + k + kof);
#pragma unroll
    for (int j = 0; j < 6; ++j) {
      bf16x8 bfr = *reinterpret_cast<const bf16x8*>(Bt + (size_t)(j * 16 + (lane & 15)) * DINNER + k + kof);
      acc[j] = __builtin_amdgcn_mfma_f32_16x16x32_bf16(af, bfr, acc[j], 0, 0, 0);
    }
  }
#pragma unroll
  for (int j = 0; j < 6; ++j) red[w][j][lane] = acc[j];
  __syncthreads();
  for (int item = tid; item < 384; item += 256) {
    int j = item >> 6, li = item & 63;
    f32x4 s = red[0][j][li];
#pragma unroll
    for (int ww = 1; ww < 4; ++ww) s += red[ww][j][li];
    int col = j * 16 + (li & 15);
    int rowb = r0 + ((li >> 4) << 2);
#pragma unroll
    for (int r = 0; r < 4; ++r) C[(size_t)(rowb + r) * NXD + col] = s[r];
  }
}

// ---------------- dt_proj (K=64) + softplus ----------------
__global__ __launch_bounds__(256) void k_dtproj(const float* __restrict__ xdbl, const bf16_t* __restrict__ Wdt,
                                                const float* __restrict__ bdt, float* __restrict__ dtf) {
  int tid = threadIdx.x, w = tid >> 6, lane = tid & 63;
  int r0 = blockIdx.y * 64 + w * 16;
  int c0 = blockIdx.x * 64;
  int arow = r0 + (lane & 15);
  int kof = (lane >> 4) * 8;
  f32x4 acc[4] = {};
#pragma unroll
  for (int ks = 0; ks < 2; ++ks) {
    int k = ks * 32;
    const float* ap = xdbl + (size_t)arow * NXD + k + kof;
    float4 a0 = *reinterpret_cast<const float4*>(ap);
    float4 a1 = *reinterpret_cast<const float4*>(ap + 4);
    bf16x8 af = { (bf16_t)a0.x, (bf16_t)a0.y, (bf16_t)a0.z, (bf16_t)a0.w,
                  (bf16_t)a1.x, (bf16_t)a1.y, (bf16_t)a1.z, (bf16_t)a1.w };
#pragma unroll
    for (int j = 0; j < 4; ++j) {
      bf16x8 bfr = *reinterpret_cast<const bf16x8*>(Wdt + (size_t)(c0 + j * 16 + (lane & 15)) * DTRANK + k + kof);
      acc[j] = __builtin_amdgcn_mfma_f32_16x16x32_bf16(af, bfr, acc[j], 0, 0, 0);
    }
  }
#pragma unroll
  for (int j = 0; j < 4; ++j) {
    int col = c0 + j * 16 + (lane & 15);
    float bb = bdt[col];
#pragma unroll
    for (int r = 0; r < 4; ++r) {
      int row = r0 + ((lane >> 4) << 2) + r;
      float v = acc[j][r] + bb;
      v = (v > 20.f) ? v : log1pf(__expf(v));
      dtf[(size_t)row * DINNER + col] = v;
    }
  }
}

// ---------------- scan pass A: per-chunk (prod dA, local h) ----------------
__global__ __launch_bounds__(256) void k_scanA(const float* __restrict__ dtf, const float* __restrict__ xsf,
                                               const float* __restrict__ xdbl, const float* __restrict__ A_log,
                                               float* __restrict__ Sp, float* __restrict__ Ss) {
  int gid = blockIdx.x * 256 + threadIdx.x;
  int c = gid & (DINNER - 1);
  int chunk = (gid >> 11) & (NC - 1);
  int b = gid >> 17;
  int t0 = b * LSEQ + chunk * CL;
  float a[16];
#pragma unroll
  for (int n = 0; n < 16; n += 4) {
    float4 al = reinterpret_cast<const float4*>(A_log + (size_t)c * 16)[n >> 2];
    a[n] = -__expf(al.x); a[n + 1] = -__expf(al.y); a[n + 2] = -__expf(al.z); a[n + 3] = -__expf(al.w);
  }
  float ap[16], h[16];
#pragma unroll
  for (int n = 0; n < 16; ++n) { ap[n] = 1.f; h[n] = 0.f; }
#pragma unroll 4
  for (int l = 0; l < CL; ++l) {
    int t = t0 + l;
    float dt = dtf[(size_t)t * DINNER + c];
    float xv = xsf[(size_t)t * DINNER + c];
    float dtx = dt * xv;
    const float4* bp = reinterpret_cast<const float4*>(xdbl + (size_t)t * NXD + DTRANK);
    float4 b0 = bp[0], b1 = bp[1], b2 = bp[2], b3 = bp[3];
    float bv[16] = { b0.x, b0.y, b0.z, b0.w, b1.x, b1.y, b1.z, b1.w,
                     b2.x, b2.y, b2.z, b2.w, b3.x, b3.y, b3.z, b3.w };
#pragma unroll
    for (int n = 0; n < 16; ++n) {
      float e = __expf(dt * a[n]);
      ap[n] *= e;
      h[n] = e * h[n] + dtx * bv[n];
    }
  }
  size_t base = ((size_t)(b * NC + chunk) * 16) * DINNER + c;
#pragma unroll
  for (int n = 0; n < 16; ++n) {
    Sp[base + (size_t)n * DINNER] = ap[n];
    Ss[base + (size_t)n * DINNER] = h[n];
  }
}

// ---------------- scan pass B: combine chunk summaries -> h_init per chunk ----------------
__global__ __launch_bounds__(256) void k_scanB(const float* __restrict__ Sp, const float* __restrict__ Ss,
                                               float* __restrict__ Hi) {
  int gid = blockIdx.x * 256 + threadIdx.x;
  int c = gid & (DINNER - 1);
  int n = (gid >> 11) & 15;
  int b = gid >> 15;
  size_t idx = ((size_t)(b * NC) * 16 + n) * DINNER + c;
  const size_t stride = (size_t)16 * DINNER;
  float h = 0.f;
#pragma unroll 4
  for (int chunk = 0; chunk < NC; ++chunk) {
    Hi[idx] = h;
    h = Sp[idx] * h + Ss[idx];
    idx += stride;
  }
}

// ---------------- scan pass C: replay with h_init, fuse y + gate -> y bf16 ----------------
__global__ __launch_bounds__(256) void k_scanC(const float* __restrict__ dtf, const float* __restrict__ xsf,
                                               const float* __restrict__ xdbl, const float* __restrict__ A_log,
                                               const float* __restrict__ Hi, const float* __restrict__ Dp,
                                               const bf16_t* __restrict__ xz, bf16_t* __restrict__ yB) {
  int gid = blockIdx.x * 256 + threadIdx.x;
  int c = gid & (DINNER - 1);
  int chunk = (gid >> 11) & (NC - 1);
  int b = gid >> 17;
  int t0 = b * LSEQ + chunk * CL;
  float a[16];
#pragma unroll
  for (int n = 0; n < 16; n += 4) {
    float4 al = reinterpret_cast<const float4*>(A_log + (size_t)c * 16)[n >> 2];
    a[n] = -__expf(al.x); a[n + 1] = -__expf(al.y); a[n + 2] = -__expf(al.z); a[n + 3] = -__expf(al.w);
  }
  float h[16];
  size_t base = ((size_t)(b * NC + chunk) * 16) * DINNER + c;
#pragma unroll
  for (int n = 0; n < 16; ++n) h[n] = Hi[base + (size_t)n * DINNER];
  float dpc = Dp[c];
#pragma unroll 4
  for (int l = 0; l < CL; ++l) {
    int t = t0 + l;
    float dt = dtf[(size_t)t * DINNER + c];
    float xv = xsf[(size_t)t * DINNER + c];
    float zv = (float)xz[(size_t)t * 4096 + DINNER + c];
    float dtx = dt * xv;
    const float4* bp = reinterpret_cast<const float4*>(xdbl + (size_t)t * NXD + DTRANK);
    float4 b0 = bp[0], b1 = bp[1], b2 = bp[2], b3 = bp[3];
    float bv[16] = { b0.x, b0.y, b0.z, b0.w, b1.x, b1.y, b1.z, b1.w,
                     b2.x, b2.y, b2.z, b2.w, b3.x, b3.y, b3.z, b3.w };
    const float4* cp = reinterpret_cast<const float4*>(xdbl + (size_t)t * NXD + DTRANK + 16);
    float4 c0 = cp[0], c1 = cp[1], c2 = cp[2], c3 = cp[3];
    float cv[16] = { c0.x, c0.y, c0.z, c0.w, c1.x, c1.y, c1.z, c1.w,
                     c2.x, c2.y, c2.z, c2.w, c3.x, c3.y, c3.z, c3.w };
    float y = 0.f;
#pragma unroll
    for (int n = 0; n < 16; ++n) {
      float e = __expf(dt * a[n]);
      h[n] = e * h[n] + dtx * bv[n];
      y += h[n] * cv[n];
    }
    y += dpc * xv;
    y *= zv / (1.f + __expf(-zv));
    yB[(size_t)t * DINNER + c] = (bf16_t)y;
  }
}

extern "C" void kernel_launch(void* const* d_in, const int* in_sizes, int n_in,
                              void* d_out, int out_size, void* d_ws, size_t ws_size,
                              hipStream_t stream) {
  (void)in_sizes; (void)n_in; (void)out_size; (void)ws_size;
  const float* x      = (const float*)d_in[0];
  const float* ln_w   = (const float*)d_in[1];
  const float* ln_b   = (const float*)d_in[2];
  const float* W_in   = (const float*)d_in[3];
  const float* conv_w = (const float*)d_in[4];
  const float* conv_b = (const float*)d_in[5];
  const float* W_x    = (const float*)d_in[6];
  const float* W_dt   = (const float*)d_in[7];
  const float* b_dt   = (const float*)d_in[8];
  const float* A_log  = (const float*)d_in[9];
  const float* Dp     = (const float*)d_in[10];
  const float* W_out  = (const float*)d_in[11];
  float* out = (float*)d_out;

  char* ws = (char*)d_ws;
  size_t off = 0;
  auto alloc = [&](size_t bytes) { void* p = ws + off; off += (bytes + 255) & ~255ull; return p; };
  bf16_t* wInB  = (bf16_t*)alloc((size_t)4096 * 1024 * 2);
  bf16_t* wXB   = (bf16_t*)alloc((size_t)96 * 2048 * 2);
  bf16_t* wDtB  = (bf16_t*)alloc((size_t)2048 * 64 * 2);
  bf16_t* wOutB = (bf16_t*)alloc((size_t)1024 * 2048 * 2);
  bf16_t* xnB   = (bf16_t*)alloc((size_t)NTOK * DMODEL * 2);
  bf16_t* xzB   = (bf16_t*)alloc((size_t)NTOK * 4096 * 2);
  float*  xsf   = (float*)alloc((size_t)NTOK * DINNER * 4);
  bf16_t* xsB   = (bf16_t*)alloc((size_t)NTOK * DINNER * 2);
  float*  xdbl  = (float*)alloc((size_t)NTOK * NXD * 4);
  float*  dtf   = (float*)alloc((size_t)NTOK * DINNER * 4);
  float*  Sp    = (float*)alloc((size_t)2 * NC * 16 * DINNER * 4);
  float*  Ss    = (float*)alloc((size_t)2 * NC * 16 * DINNER * 4);
  float*  Hi    = (float*)alloc((size_t)2 * NC * 16 * DINNER * 4);
  bf16_t* yB    = (bf16_t*)alloc((size_t)NTOK * DINNER * 2);
  float*  Pq    = (float*)alloc((size_t)4 * NTOK * 1024 * 4);   // split-K partials

  // fused weight conversion
  k_cvt4<<<(CVT_N3 + 255) / 256, 256, 0, stream>>>(W_in, W_x, W_dt, W_out, wInB, wXB, wDtB, wOutB);

  // layernorm
  k_ln<<<NTOK, 256, 0, stream>>>(x, ln_w, ln_b, xnB);

  // in_proj: xz[2048][4096] bf16
  k_gemm<128, false, true><<<dim3(4096 / 128, NTOK / 128), 256, 0, stream>>>(xnB, wInB, xzB, nullptr, 4096, 1024);

  // conv + silu
  k_conv<<<NTOK * DINNER / 256, 256, 0, stream>>>(xzB, conv_w, conv_b, xsf, xsB);

  // x_proj (K-split across 4 waves)
  k_xproj<<<NTOK / 16, 256, 0, stream>>>(xsB, wXB, xdbl);

  // dt_proj + softplus
  k_dtproj<<<dim3(DINNER / 64, NTOK / 64), 256, 0, stream>>>(xdbl, wDtB, b_dt, dtf);

  // chunked scan (NC=64 -> 1024 blocks for A/C)
  k_scanA<<<2 * NC * DINNER / 256, 256, 0, stream>>>(dtf, xsf, xdbl, A_log, Sp, Ss);
  k_scanB<<<2 * 16 * DINNER / 256, 256, 0, stream>>>(Sp, Ss, Hi);
  k_scanC<<<2 * NC * DINNER / 256, 256, 0, stream>>>(dtf, xsf, xdbl, A_log, Hi, Dp, xzB, yB);

  // out_proj: split-K x4 (512 WGs, 2 blocks/CU) + reduce with residual
  k_gemmsk<<<dim3(8, 64), 256, 0, stream>>>(yB, wOutB, Pq);
  k_red<<<NTOK * 1024 / 4 / 256, 256, 0, stream>>>(Pq, x, out);
}

// Round 13
// 258.392 us; speedup vs baseline: 1.5668x; 1.0506x over previous
//
#include <hip/hip_runtime.h>

typedef __bf16 bf16_t;
typedef __bf16 bf16x8 __attribute__((ext_vector_type(8)));
typedef __bf16 bf16x4 __attribute__((ext_vector_type(4)));
typedef float f32x4 __attribute__((ext_vector_type(4)));
typedef unsigned int u32;

#define NTOK 2048   // B*L
#define LSEQ 1024
#define DMODEL 1024
#define DINNER 2048
#define NXD 96      // DT_RANK + 2*D_STATE
#define DTRANK 64
#define NC 64       // scan chunks per sequence
#define CL 16       // chunk length (NC*CL == LSEQ)

__device__ __forceinline__ void gload16(const void* g, void* l) {
  __builtin_amdgcn_global_load_lds((const __attribute__((address_space(1))) u32*)g,
                                   (__attribute__((address_space(3))) u32*)l, 16, 0, 0);
}

// ---------------- fused fp32 -> bf16 weight convert (4 arrays, 1 launch) ----------------
#define CVT_N0 1048576            // W_in  / 4
#define CVT_N1 (CVT_N0 + 49152)   // + W_x / 4
#define CVT_N2 (CVT_N1 + 32768)   // + W_dt / 4
#define CVT_N3 (CVT_N2 + 524288)  // + W_out / 4
__global__ __launch_bounds__(256) void k_cvt4(const float* __restrict__ a0, const float* __restrict__ a1,
                                              const float* __restrict__ a2, const float* __restrict__ a3,
                                              bf16_t* __restrict__ o0, bf16_t* __restrict__ o1,
                                              bf16_t* __restrict__ o2, bf16_t* __restrict__ o3) {
  int i = blockIdx.x * 256 + threadIdx.x;
  const float* src; bf16_t* dst; int idx;
  if (i < CVT_N0)      { src = a0; dst = o0; idx = i; }
  else if (i < CVT_N1) { src = a1; dst = o1; idx = i - CVT_N0; }
  else if (i < CVT_N2) { src = a2; dst = o2; idx = i - CVT_N1; }
  else if (i < CVT_N3) { src = a3; dst = o3; idx = i - CVT_N2; }
  else return;
  float4 v = reinterpret_cast<const float4*>(src)[idx];
  bf16x4 o = { (bf16_t)v.x, (bf16_t)v.y, (bf16_t)v.z, (bf16_t)v.w };
  reinterpret_cast<bf16x4*>(dst)[idx] = o;
}

// ---------------- LayerNorm -> bf16 ----------------
__global__ __launch_bounds__(256) void k_ln(const float* __restrict__ x, const float* __restrict__ w,
                                            const float* __restrict__ b, bf16_t* __restrict__ xn) {
  const int row = blockIdx.x;
  const int tid = threadIdx.x;
  float4 v = reinterpret_cast<const float4*>(x + (size_t)row * DMODEL)[tid];
  float s = v.x + v.y + v.z + v.w;
  float q = v.x*v.x + v.y*v.y + v.z*v.z + v.w*v.w;
#pragma unroll
  for (int o = 32; o > 0; o >>= 1) { s += __shfl_down(s, o); q += __shfl_down(q, o); }
  __shared__ float sh[8];
  int wv = tid >> 6;
  if ((tid & 63) == 0) { sh[wv] = s; sh[4 + wv] = q; }
  __syncthreads();
  if (tid == 0) {
    sh[0] = sh[0] + sh[1] + sh[2] + sh[3];
    sh[4] = sh[4] + sh[5] + sh[6] + sh[7];
  }
  __syncthreads();
  float mu = sh[0] * (1.f / DMODEL);
  float var = sh[4] * (1.f / DMODEL) - mu * mu;
  float rs = rsqrtf(var + 1e-5f);
  float4 w4 = reinterpret_cast<const float4*>(w)[tid];
  float4 b4 = reinterpret_cast<const float4*>(b)[tid];
  bf16x4 o = { (bf16_t)((v.x - mu) * rs * w4.x + b4.x),
               (bf16_t)((v.y - mu) * rs * w4.y + b4.y),
               (bf16_t)((v.z - mu) * rs * w4.z + b4.z),
               (bf16_t)((v.w - mu) * rs * w4.w + b4.w) };
  reinterpret_cast<bf16x4*>(xn + (size_t)row * DMODEL)[tid] = o;
}

// LDS slot swizzle: slot' = slot ^ ((row>>2)&3). Applied to global SOURCE (staging)
// and ds_read side; LDS dest stays linear (global_load_lds constraint, rule #21).

// ---------------- BMx128 MFMA GEMM, C = A(MxK) * Bt(NxK)^T [+ resid], XCD-swizzled ----------------
template <int BM, bool RESID, bool OUTBF>
__global__ __launch_bounds__(256) void k_gemm(const bf16_t* __restrict__ A, const bf16_t* __restrict__ Bt,
                                              void* __restrict__ Cout, const float* __restrict__ R,
                                              int N, int K) {
  constexpr int BN = 128;
  constexpr int MR = BM / 32;
  constexpr int NCHUNK = (BM + BN) * 4;
  constexpr int ITER = NCHUNK / 256;
  __shared__ bf16_t As[BM * 32];
  __shared__ bf16_t Bs[BN * 32];
  const int tid = threadIdx.x;
  const int w = tid >> 6, lane = tid & 63;

  // XCD-aware swizzle (nwg % 8 == 0 for all our launches)
  const int nbx = gridDim.x;
  int nwg = gridDim.x * gridDim.y;
  int orig = blockIdx.y * gridDim.x + blockIdx.x;
  int cpx = nwg >> 3;
  int swz = (orig & 7) * cpx + (orig >> 3);
  int bx = swz % nbx, by = swz / nbx;
  const int brow = by * BM, bcol = bx * BN;
  const int wr = (w >> 1) * (BM / 2), wc = (w & 1) * 64;

  const bf16_t* gsrc[ITER];
  bf16_t* lbase[ITER];
#pragma unroll
  for (int i = 0; i < ITER; ++i) {
    int p0 = i * 256 + w * 64;
    int p = p0 + lane;
    if (p0 < BM * 4) {
      int r = p >> 2, s = (p & 3) ^ ((r >> 2) & 3);
      gsrc[i] = A + (size_t)(brow + r) * K + s * 8;
      lbase[i] = &As[p0 * 8];
    } else {
      int q = p - BM * 4;
      int r = q >> 2, s = (q & 3) ^ ((r >> 2) & 3);
      gsrc[i] = Bt + (size_t)(bcol + r) * K + s * 8;
      lbase[i] = &Bs[(p0 - BM * 4) * 8];
    }
  }

  f32x4 acc[MR][4] = {};
  for (int kk = 0; kk < K; kk += 32) {
    __syncthreads();
#pragma unroll
    for (int i = 0; i < ITER; ++i) gload16(gsrc[i] + kk, lbase[i]);
    __syncthreads();
    bf16x8 af[MR], bfr[4];
#pragma unroll
    for (int m = 0; m < MR; ++m) {
      int rr = wr + m * 16 + (lane & 15);
      af[m] = *reinterpret_cast<const bf16x8*>(&As[rr * 32 + (((lane >> 4) ^ ((rr >> 2) & 3)) << 3)]);
    }
#pragma unroll
    for (int n = 0; n < 4; ++n) {
      int rc = wc + n * 16 + (lane & 15);
      bfr[n] = *reinterpret_cast<const bf16x8*>(&Bs[rc * 32 + (((lane >> 4) ^ ((rc >> 2) & 3)) << 3)]);
    }
#pragma unroll
    for (int m = 0; m < MR; ++m)
#pragma unroll
      for (int n = 0; n < 4; ++n)
        acc[m][n] = __builtin_amdgcn_mfma_f32_16x16x32_bf16(af[m], bfr[n], acc[m][n], 0, 0, 0);
  }

#pragma unroll
  for (int m = 0; m < MR; ++m) {
#pragma unroll
    for (int n = 0; n < 4; ++n) {
      int col = bcol + wc + n * 16 + (lane & 15);
#pragma unroll
      for (int r = 0; r < 4; ++r) {
        int row = brow + wr + m * 16 + ((lane >> 4) << 2) + r;
        float v = acc[m][n][r];
        if (RESID) v += R[(size_t)row * N + col];
        if (OUTBF) ((bf16_t*)Cout)[(size_t)row * N + col] = (bf16_t)v;
        else       ((float*)Cout)[(size_t)row * N + col] = v;
      }
    }
  }
}

// ---------------- out_proj split-K GEMM: P[split] = yB * W_out^T over K-slice ----------------
// grid dim3(8, 64): byf = (rowblk<<2)|split ; 512 WGs = 2 blocks/CU
__global__ __launch_bounds__(256) void k_gemmsk(const bf16_t* __restrict__ A, const bf16_t* __restrict__ Bt,
                                                float* __restrict__ P) {
  constexpr int BM = 128, BN = 128, K = 2048, N = 1024, KSP = 512;
  __shared__ bf16_t As[BM * 32];
  __shared__ bf16_t Bs[BN * 32];
  const int tid = threadIdx.x, w = tid >> 6, lane = tid & 63;
  const int nbx = gridDim.x;
  int nwg = gridDim.x * gridDim.y;
  int orig = blockIdx.y * gridDim.x + blockIdx.x;
  int cpx = nwg >> 3;
  int swz = (orig & 7) * cpx + (orig >> 3);
  int bx = swz % nbx, byf = swz / nbx;
  const int split = byf & 3, by = byf >> 2;
  const int brow = by * BM, bcol = bx * BN;
  const int wr = (w >> 1) * 64, wc = (w & 1) * 64;
  const int k0 = split * KSP;

  const bf16_t* gsrc[4];
  bf16_t* lbase[4];
#pragma unroll
  for (int i = 0; i < 4; ++i) {
    int p0 = i * 256 + w * 64;
    int p = p0 + lane;
    if (p0 < BM * 4) {
      int r = p >> 2, s = (p & 3) ^ ((r >> 2) & 3);
      gsrc[i] = A + (size_t)(brow + r) * K + s * 8;
      lbase[i] = &As[p0 * 8];
    } else {
      int q = p - BM * 4;
      int r = q >> 2, s = (q & 3) ^ ((r >> 2) & 3);
      gsrc[i] = Bt + (size_t)(bcol + r) * K + s * 8;
      lbase[i] = &Bs[(p0 - BM * 4) * 8];
    }
  }

  f32x4 acc[4][4] = {};
  for (int kk = k0; kk < k0 + KSP; kk += 32) {
    __syncthreads();
#pragma unroll
    for (int i = 0; i < 4; ++i) gload16(gsrc[i] + kk, lbase[i]);
    __syncthreads();
    bf16x8 af[4], bfr[4];
#pragma unroll
    for (int m = 0; m < 4; ++m) {
      int rr = wr + m * 16 + (lane & 15);
      af[m] = *reinterpret_cast<const bf16x8*>(&As[rr * 32 + (((lane >> 4) ^ ((rr >> 2) & 3)) << 3)]);
    }
#pragma unroll
    for (int n = 0; n < 4; ++n) {
      int rc = wc + n * 16 + (lane & 15);
      bfr[n] = *reinterpret_cast<const bf16x8*>(&Bs[rc * 32 + (((lane >> 4) ^ ((rc >> 2) & 3)) << 3)]);
    }
#pragma unroll
    for (int m = 0; m < 4; ++m)
#pragma unroll
      for (int n = 0; n < 4; ++n)
        acc[m][n] = __builtin_amdgcn_mfma_f32_16x16x32_bf16(af[m], bfr[n], acc[m][n], 0, 0, 0);
  }

  float* Pp = P + (size_t)split * ((size_t)NTOK * N);
#pragma unroll
  for (int m = 0; m < 4; ++m)
#pragma unroll
    for (int n = 0; n < 4; ++n) {
      int col = bcol + wc + n * 16 + (lane & 15);
#pragma unroll
      for (int r = 0; r < 4; ++r) {
        int row = brow + wr + m * 16 + ((lane >> 4) << 2) + r;
        Pp[(size_t)row * N + col] = acc[m][n][r];
      }
    }
}

// ---------------- split-K reduce + residual ----------------
__global__ __launch_bounds__(256) void k_red(const float* __restrict__ P, const float* __restrict__ x,
                                             float* __restrict__ out) {
  int i = blockIdx.x * 256 + threadIdx.x;   // float4 index, 2048*1024/4 total
  constexpr size_t S = (size_t)NTOK * 1024 / 4;
  float4 a = reinterpret_cast<const float4*>(P)[i];
  float4 b = reinterpret_cast<const float4*>(P)[i + S];
  float4 c = reinterpret_cast<const float4*>(P)[i + 2 * S];
  float4 d = reinterpret_cast<const float4*>(P)[i + 3 * S];
  float4 xv = reinterpret_cast<const float4*>(x)[i];
  float4 o = { a.x + b.x + c.x + d.x + xv.x,
               a.y + b.y + c.y + d.y + xv.y,
               a.z + b.z + c.z + d.z + xv.z,
               a.w + b.w + c.w + d.w + xv.w };
  reinterpret_cast<float4*>(out)[i] = o;
}

// ---------------- depthwise causal conv1d + SiLU (bf16 in, bf16 out only) ----------------
__global__ __launch_bounds__(256) void k_conv(const bf16_t* __restrict__ xz, const float* __restrict__ cw,
                                              const float* __restrict__ cb, bf16_t* __restrict__ xsB) {
  int gid = blockIdx.x * 256 + threadIdx.x;
  int c = gid & (DINNER - 1);
  int t = gid >> 11;
  int l = t & (LSEQ - 1);
  float4 w4 = reinterpret_cast<const float4*>(cw)[c];
  float wk[4] = { w4.x, w4.y, w4.z, w4.w };
  float v = cb[c];
#pragma unroll
  for (int k = 0; k < 4; ++k) {
    int ll = l + k - 3;
    if (ll >= 0) v += wk[k] * (float)xz[(size_t)(t + k - 3) * 4096 + c];
  }
  float sv = v / (1.f + __expf(-v));
  xsB[(size_t)t * DINNER + c] = (bf16_t)sv;
}

// ---------------- x_proj: xdbl[2048][96] = xs(bf16) @ W_x^T, K split across 4 waves ----------------
__global__ __launch_bounds__(256) void k_xproj(const bf16_t* __restrict__ A, const bf16_t* __restrict__ Bt,
                                               float* __restrict__ C) {
  __shared__ f32x4 red[4][6][64];
  int tid = threadIdx.x, w = tid >> 6, lane = tid & 63;
  int r0 = blockIdx.x * 16;
  int arow = r0 + (lane & 15);
  int kof = (lane >> 4) * 8;
  f32x4 acc[6] = {};
  for (int k = w * 512; k < (w + 1) * 512; k += 32) {
    bf16x8 af = *reinterpret_cast<const bf16x8*>(A + (size_t)arow * DINNER + k + kof);
#pragma unroll
    for (int j = 0; j < 6; ++j) {
      bf16x8 bfr = *reinterpret_cast<const bf16x8*>(Bt + (size_t)(j * 16 + (lane & 15)) * DINNER + k + kof);
      acc[j] = __builtin_amdgcn_mfma_f32_16x16x32_bf16(af, bfr, acc[j], 0, 0, 0);
    }
  }
#pragma unroll
  for (int j = 0; j < 6; ++j) red[w][j][lane] = acc[j];
  __syncthreads();
  for (int item = tid; item < 384; item += 256) {
    int j = item >> 6, li = item & 63;
    f32x4 s = red[0][j][li];
#pragma unroll
    for (int ww = 1; ww < 4; ++ww) s += red[ww][j][li];
    int col = j * 16 + (li & 15);
    int rowb = r0 + ((li >> 4) << 2);
#pragma unroll
    for (int r = 0; r < 4; ++r) C[(size_t)(rowb + r) * NXD + col] = s[r];
  }
}

// ---------------- dt_proj (K=64) + softplus -> bf16 ----------------
__global__ __launch_bounds__(256) void k_dtproj(const float* __restrict__ xdbl, const bf16_t* __restrict__ Wdt,
                                                const float* __restrict__ bdt, bf16_t* __restrict__ dtf) {
  int tid = threadIdx.x, w = tid >> 6, lane = tid & 63;
  int r0 = blockIdx.y * 64 + w * 16;
  int c0 = blockIdx.x * 64;
  int arow = r0 + (lane & 15);
  int kof = (lane >> 4) * 8;
  f32x4 acc[4] = {};
#pragma unroll
  for (int ks = 0; ks < 2; ++ks) {
    int k = ks * 32;
    const float* ap = xdbl + (size_t)arow * NXD + k + kof;
    float4 a0 = *reinterpret_cast<const float4*>(ap);
    float4 a1 = *reinterpret_cast<const float4*>(ap + 4);
    bf16x8 af = { (bf16_t)a0.x, (bf16_t)a0.y, (bf16_t)a0.z, (bf16_t)a0.w,
                  (bf16_t)a1.x, (bf16_t)a1.y, (bf16_t)a1.z, (bf16_t)a1.w };
#pragma unroll
    for (int j = 0; j < 4; ++j) {
      bf16x8 bfr = *reinterpret_cast<const bf16x8*>(Wdt + (size_t)(c0 + j * 16 + (lane & 15)) * DTRANK + k + kof);
      acc[j] = __builtin_amdgcn_mfma_f32_16x16x32_bf16(af, bfr, acc[j], 0, 0, 0);
    }
  }
#pragma unroll
  for (int j = 0; j < 4; ++j) {
    int col = c0 + j * 16 + (lane & 15);
    float bb = bdt[col];
#pragma unroll
    for (int r = 0; r < 4; ++r) {
      int row = r0 + ((lane >> 4) << 2) + r;
      float v = acc[j][r] + bb;
      v = (v > 20.f) ? v : log1pf(__expf(v));
      dtf[(size_t)row * DINNER + col] = (bf16_t)v;
    }
  }
}

// ---------------- scan pass A: per-chunk (prod dA, local h); dt/x hoisted ----------------
__global__ __launch_bounds__(256) void k_scanA(const bf16_t* __restrict__ dtf, const bf16_t* __restrict__ xs,
                                               const float* __restrict__ xdbl, const float* __restrict__ A_log,
                                               float* __restrict__ Sp, float* __restrict__ Ss) {
  int gid = blockIdx.x * 256 + threadIdx.x;
  int c = gid & (DINNER - 1);
  int chunk = (gid >> 11) & (NC - 1);
  int b = gid >> 17;
  int t0 = b * LSEQ + chunk * CL;
  // hoisted per-t scalar loads: 32 independent loads pipeline under one latency window
  float dt16[CL], xv16[CL];
#pragma unroll
  for (int l = 0; l < CL; ++l) {
    dt16[l] = (float)dtf[(size_t)(t0 + l) * DINNER + c];
    xv16[l] = (float)xs[(size_t)(t0 + l) * DINNER + c];
  }
  float a[16];
#pragma unroll
  for (int n = 0; n < 16; n += 4) {
    float4 al = reinterpret_cast<const float4*>(A_log + (size_t)c * 16)[n >> 2];
    a[n] = -__expf(al.x); a[n + 1] = -__expf(al.y); a[n + 2] = -__expf(al.z); a[n + 3] = -__expf(al.w);
  }
  float ap[16], h[16];
#pragma unroll
  for (int n = 0; n < 16; ++n) { ap[n] = 1.f; h[n] = 0.f; }
#pragma unroll
  for (int l = 0; l < CL; ++l) {
    int t = t0 + l;
    float dt = dt16[l];
    float dtx = dt * xv16[l];
    const float4* bp = reinterpret_cast<const float4*>(xdbl + (size_t)t * NXD + DTRANK);
    float4 b0 = bp[0], b1 = bp[1], b2 = bp[2], b3 = bp[3];
    float bv[16] = { b0.x, b0.y, b0.z, b0.w, b1.x, b1.y, b1.z, b1.w,
                     b2.x, b2.y, b2.z, b2.w, b3.x, b3.y, b3.z, b3.w };
#pragma unroll
    for (int n = 0; n < 16; ++n) {
      float e = __expf(dt * a[n]);
      ap[n] *= e;
      h[n] = e * h[n] + dtx * bv[n];
    }
  }
  size_t base = ((size_t)(b * NC + chunk) * 16) * DINNER + c;
#pragma unroll
  for (int n = 0; n < 16; ++n) {
    Sp[base + (size_t)n * DINNER] = ap[n];
    Ss[base + (size_t)n * DINNER] = h[n];
  }
}

// ---------------- scan pass B: combine chunk summaries -> h_init per chunk ----------------
__global__ __launch_bounds__(256) void k_scanB(const float* __restrict__ Sp, const float* __restrict__ Ss,
                                               float* __restrict__ Hi) {
  int gid = blockIdx.x * 256 + threadIdx.x;
  int c = gid & (DINNER - 1);
  int n = (gid >> 11) & 15;
  int b = gid >> 15;
  size_t idx = ((size_t)(b * NC) * 16 + n) * DINNER + c;
  const size_t stride = (size_t)16 * DINNER;
  float h = 0.f;
#pragma unroll 4
  for (int chunk = 0; chunk < NC; ++chunk) {
    Hi[idx] = h;
    h = Sp[idx] * h + Ss[idx];
    idx += stride;
  }
}

// ---------------- scan pass C: replay with h_init, fuse y + gate -> y bf16; dt/x/z hoisted ----------------
__global__ __launch_bounds__(256) void k_scanC(const bf16_t* __restrict__ dtf, const bf16_t* __restrict__ xs,
                                               const float* __restrict__ xdbl, const float* __restrict__ A_log,
                                               const float* __restrict__ Hi, const float* __restrict__ Dp,
                                               const bf16_t* __restrict__ xz, bf16_t* __restrict__ yB) {
  int gid = blockIdx.x * 256 + threadIdx.x;
  int c = gid & (DINNER - 1);
  int chunk = (gid >> 11) & (NC - 1);
  int b = gid >> 17;
  int t0 = b * LSEQ + chunk * CL;
  // hoisted per-t scalar loads: 48 independent loads pipeline under one latency window
  float dt16[CL], xv16[CL], zv16[CL];
#pragma unroll
  for (int l = 0; l < CL; ++l) {
    dt16[l] = (float)dtf[(size_t)(t0 + l) * DINNER + c];
    xv16[l] = (float)xs[(size_t)(t0 + l) * DINNER + c];
    zv16[l] = (float)xz[(size_t)(t0 + l) * 4096 + DINNER + c];
  }
  float a[16];
#pragma unroll
  for (int n = 0; n < 16; n += 4) {
    float4 al = reinterpret_cast<const float4*>(A_log + (size_t)c * 16)[n >> 2];
    a[n] = -__expf(al.x); a[n + 1] = -__expf(al.y); a[n + 2] = -__expf(al.z); a[n + 3] = -__expf(al.w);
  }
  float h[16];
  size_t base = ((size_t)(b * NC + chunk) * 16) * DINNER + c;
#pragma unroll
  for (int n = 0; n < 16; ++n) h[n] = Hi[base + (size_t)n * DINNER];
  float dpc = Dp[c];
#pragma unroll
  for (int l = 0; l < CL; ++l) {
    int t = t0 + l;
    float dt = dt16[l];
    float xv = xv16[l];
    float zv = zv16[l];
    float dtx = dt * xv;
    const float4* bp = reinterpret_cast<const float4*>(xdbl + (size_t)t * NXD + DTRANK);
    float4 b0 = bp[0], b1 = bp[1], b2 = bp[2], b3 = bp[3];
    float bv[16] = { b0.x, b0.y, b0.z, b0.w, b1.x, b1.y, b1.z, b1.w,
                     b2.x, b2.y, b2.z, b2.w, b3.x, b3.y, b3.z, b3.w };
    const float4* cp = reinterpret_cast<const float4*>(xdbl + (size_t)t * NXD + DTRANK + 16);
    float4 c0 = cp[0], c1 = cp[1], c2 = cp[2], c3 = cp[3];
    float cv[16] = { c0.x, c0.y, c0.z, c0.w, c1.x, c1.y, c1.z, c1.w,
                     c2.x, c2.y, c2.z, c2.w, c3.x, c3.y, c3.z, c3.w };
    float y = 0.f;
#pragma unroll
    for (int n = 0; n < 16; ++n) {
      float e = __expf(dt * a[n]);
      h[n] = e * h[n] + dtx * bv[n];
      y += h[n] * cv[n];
    }
    y += dpc * xv;
    y *= zv / (1.f + __expf(-zv));
    yB[(size_t)t * DINNER + c] = (bf16_t)y;
  }
}

extern "C" void kernel_launch(void* const* d_in, const int* in_sizes, int n_in,
                              void* d_out, int out_size, void* d_ws, size_t ws_size,
                              hipStream_t stream) {
  (void)in_sizes; (void)n_in; (void)out_size; (void)ws_size;
  const float* x      = (const float*)d_in[0];
  const float* ln_w   = (const float*)d_in[1];
  const float* ln_b   = (const float*)d_in[2];
  const float* W_in   = (const float*)d_in[3];
  const float* conv_w = (const float*)d_in[4];
  const float* conv_b = (const float*)d_in[5];
  const float* W_x    = (const float*)d_in[6];
  const float* W_dt   = (const float*)d_in[7];
  const float* b_dt   = (const float*)d_in[8];
  const float* A_log  = (const float*)d_in[9];
  const float* Dp     = (const float*)d_in[10];
  const float* W_out  = (const float*)d_in[11];
  float* out = (float*)d_out;

  char* ws = (char*)d_ws;
  size_t off = 0;
  auto alloc = [&](size_t bytes) { void* p = ws + off; off += (bytes + 255) & ~255ull; return p; };
  bf16_t* wInB  = (bf16_t*)alloc((size_t)4096 * 1024 * 2);
  bf16_t* wXB   = (bf16_t*)alloc((size_t)96 * 2048 * 2);
  bf16_t* wDtB  = (bf16_t*)alloc((size_t)2048 * 64 * 2);
  bf16_t* wOutB = (bf16_t*)alloc((size_t)1024 * 2048 * 2);
  bf16_t* xnB   = (bf16_t*)alloc((size_t)NTOK * DMODEL * 2);
  bf16_t* xzB   = (bf16_t*)alloc((size_t)NTOK * 4096 * 2);
  bf16_t* xsB   = (bf16_t*)alloc((size_t)NTOK * DINNER * 2);
  float*  xdbl  = (float*)alloc((size_t)NTOK * NXD * 4);
  bf16_t* dtfB  = (bf16_t*)alloc((size_t)NTOK * DINNER * 2);
  float*  Sp    = (float*)alloc((size_t)2 * NC * 16 * DINNER * 4);
  float*  Ss    = (float*)alloc((size_t)2 * NC * 16 * DINNER * 4);
  float*  Hi    = (float*)alloc((size_t)2 * NC * 16 * DINNER * 4);
  bf16_t* yB    = (bf16_t*)alloc((size_t)NTOK * DINNER * 2);
  float*  Pq    = (float*)alloc((size_t)4 * NTOK * 1024 * 4);   // split-K partials

  // fused weight conversion
  k_cvt4<<<(CVT_N3 + 255) / 256, 256, 0, stream>>>(W_in, W_x, W_dt, W_out, wInB, wXB, wDtB, wOutB);

  // layernorm
  k_ln<<<NTOK, 256, 0, stream>>>(x, ln_w, ln_b, xnB);

  // in_proj: xz[2048][4096] bf16
  k_gemm<128, false, true><<<dim3(4096 / 128, NTOK / 128), 256, 0, stream>>>(xnB, wInB, xzB, nullptr, 4096, 1024);

  // conv + silu (bf16 out only)
  k_conv<<<NTOK * DINNER / 256, 256, 0, stream>>>(xzB, conv_w, conv_b, xsB);

  // x_proj (K-split across 4 waves)
  k_xproj<<<NTOK / 16, 256, 0, stream>>>(xsB, wXB, xdbl);

  // dt_proj + softplus -> bf16
  k_dtproj<<<dim3(DINNER / 64, NTOK / 64), 256, 0, stream>>>(xdbl, wDtB, b_dt, dtfB);

  // chunked scan (NC=64 -> 1024 blocks for A/C)
  k_scanA<<<2 * NC * DINNER / 256, 256, 0, stream>>>(dtfB, xsB, xdbl, A_log, Sp, Ss);
  k_scanB<<<2 * 16 * DINNER / 256, 256, 0, stream>>>(Sp, Ss, Hi);
  k_scanC<<<2 * NC * DINNER / 256, 256, 0, stream>>>(dtfB, xsB, xdbl, A_log, Hi, Dp, xzB, yB);

  // out_proj: split-K x4 (512 WGs, 2 blocks/CU) + reduce with residual
  k_gemmsk<<<dim3(8, 64), 256, 0, stream>>>(yB, wOutB, Pq);
  k_red<<<NTOK * 1024 / 4 / 256, 256, 0, stream>>>(Pq, x, out);
}

// Round 14
// 248.632 us; speedup vs baseline: 1.6283x; 1.0393x over previous
//
#include <hip/hip_runtime.h>

typedef __bf16 bf16_t;
typedef __bf16 bf16x8 __attribute__((ext_vector_type(8)));
typedef __bf16 bf16x4 __attribute__((ext_vector_type(4)));
typedef float f32x4 __attribute__((ext_vector_type(4)));
typedef unsigned int u32;
typedef unsigned short u16;

#define NTOK 2048   // B*L
#define LSEQ 1024
#define DMODEL 1024
#define DINNER 2048
#define NXD 96      // DT_RANK + 2*D_STATE
#define DTRANK 64
#define NC 64       // scan chunks per sequence
#define CL 16       // chunk length (NC*CL == LSEQ)

__device__ __forceinline__ void gload16(const void* g, void* l) {
  __builtin_amdgcn_global_load_lds((const __attribute__((address_space(1))) u32*)g,
                                   (__attribute__((address_space(3))) u32*)l, 16, 0, 0);
}

__device__ __forceinline__ u32 pack2(float a, float b) {
  u16 ua = __builtin_bit_cast(u16, (bf16_t)a);
  u16 ub = __builtin_bit_cast(u16, (bf16_t)b);
  return (u32)ua | ((u32)ub << 16);
}
__device__ __forceinline__ float lo2f(u32 v) { return (float)__builtin_bit_cast(bf16_t, (u16)(v & 0xffff)); }
__device__ __forceinline__ float hi2f(u32 v) { return (float)__builtin_bit_cast(bf16_t, (u16)(v >> 16)); }

// ---------------- fused LayerNorm (blocks 0..2047) + fp32->bf16 weight cvt (rest) ----------------
#define CVT_N0 1048576            // W_in  / 4
#define CVT_N1 (CVT_N0 + 49152)   // + W_x / 4
#define CVT_N2 (CVT_N1 + 32768)   // + W_dt / 4
#define CVT_N3 (CVT_N2 + 524288)  // + W_out / 4   (== 1654784, /256 == 6464)
__global__ __launch_bounds__(256) void k_lncvt(const float* __restrict__ x, const float* __restrict__ w,
                                               const float* __restrict__ b, bf16_t* __restrict__ xn,
                                               const float* __restrict__ a0, const float* __restrict__ a1,
                                               const float* __restrict__ a2, const float* __restrict__ a3,
                                               bf16_t* __restrict__ o0, bf16_t* __restrict__ o1,
                                               bf16_t* __restrict__ o2, bf16_t* __restrict__ o3) {
  const int tid = threadIdx.x;
  if (blockIdx.x < NTOK) {
    const int row = blockIdx.x;
    float4 v = reinterpret_cast<const float4*>(x + (size_t)row * DMODEL)[tid];
    float s = v.x + v.y + v.z + v.w;
    float q = v.x*v.x + v.y*v.y + v.z*v.z + v.w*v.w;
#pragma unroll
    for (int o = 32; o > 0; o >>= 1) { s += __shfl_down(s, o); q += __shfl_down(q, o); }
    __shared__ float sh[8];
    int wv = tid >> 6;
    if ((tid & 63) == 0) { sh[wv] = s; sh[4 + wv] = q; }
    __syncthreads();
    if (tid == 0) {
      sh[0] = sh[0] + sh[1] + sh[2] + sh[3];
      sh[4] = sh[4] + sh[5] + sh[6] + sh[7];
    }
    __syncthreads();
    float mu = sh[0] * (1.f / DMODEL);
    float var = sh[4] * (1.f / DMODEL) - mu * mu;
    float rs = rsqrtf(var + 1e-5f);
    float4 w4 = reinterpret_cast<const float4*>(w)[tid];
    float4 b4 = reinterpret_cast<const float4*>(b)[tid];
    bf16x4 o = { (bf16_t)((v.x - mu) * rs * w4.x + b4.x),
                 (bf16_t)((v.y - mu) * rs * w4.y + b4.y),
                 (bf16_t)((v.z - mu) * rs * w4.z + b4.z),
                 (bf16_t)((v.w - mu) * rs * w4.w + b4.w) };
    reinterpret_cast<bf16x4*>(xn + (size_t)row * DMODEL)[tid] = o;
    return;
  }
  int i = (blockIdx.x - NTOK) * 256 + tid;
  const float* src; bf16_t* dst; int idx;
  if (i < CVT_N0)      { src = a0; dst = o0; idx = i; }
  else if (i < CVT_N1) { src = a1; dst = o1; idx = i - CVT_N0; }
  else if (i < CVT_N2) { src = a2; dst = o2; idx = i - CVT_N1; }
  else                 { src = a3; dst = o3; idx = i - CVT_N2; }
  float4 v = reinterpret_cast<const float4*>(src)[idx];
  bf16x4 o = { (bf16_t)v.x, (bf16_t)v.y, (bf16_t)v.z, (bf16_t)v.w };
  reinterpret_cast<bf16x4*>(dst)[idx] = o;
}

// LDS slot swizzle: slot' = slot ^ ((row>>2)&3). Applied to global SOURCE (staging)
// and ds_read side; LDS dest stays linear (global_load_lds constraint, rule #21).

// ---------------- BMx128 MFMA GEMM, C = A(MxK) * Bt(NxK)^T, XCD-swizzled ----------------
template <int BM, bool OUTBF>
__global__ __launch_bounds__(256) void k_gemm(const bf16_t* __restrict__ A, const bf16_t* __restrict__ Bt,
                                              void* __restrict__ Cout, int N, int K) {
  constexpr int BN = 128;
  constexpr int MR = BM / 32;
  constexpr int NCHUNK = (BM + BN) * 4;
  constexpr int ITER = NCHUNK / 256;
  __shared__ bf16_t As[BM * 32];
  __shared__ bf16_t Bs[BN * 32];
  const int tid = threadIdx.x;
  const int w = tid >> 6, lane = tid & 63;

  const int nbx = gridDim.x;
  int nwg = gridDim.x * gridDim.y;
  int orig = blockIdx.y * gridDim.x + blockIdx.x;
  int cpx = nwg >> 3;
  int swz = (orig & 7) * cpx + (orig >> 3);
  int bx = swz % nbx, by = swz / nbx;
  const int brow = by * BM, bcol = bx * BN;
  const int wr = (w >> 1) * (BM / 2), wc = (w & 1) * 64;

  const bf16_t* gsrc[ITER];
  bf16_t* lbase[ITER];
#pragma unroll
  for (int i = 0; i < ITER; ++i) {
    int p0 = i * 256 + w * 64;
    int p = p0 + lane;
    if (p0 < BM * 4) {
      int r = p >> 2, s = (p & 3) ^ ((r >> 2) & 3);
      gsrc[i] = A + (size_t)(brow + r) * K + s * 8;
      lbase[i] = &As[p0 * 8];
    } else {
      int q = p - BM * 4;
      int r = q >> 2, s = (q & 3) ^ ((r >> 2) & 3);
      gsrc[i] = Bt + (size_t)(bcol + r) * K + s * 8;
      lbase[i] = &Bs[(p0 - BM * 4) * 8];
    }
  }

  f32x4 acc[MR][4] = {};
  for (int kk = 0; kk < K; kk += 32) {
    __syncthreads();
#pragma unroll
    for (int i = 0; i < ITER; ++i) gload16(gsrc[i] + kk, lbase[i]);
    __syncthreads();
    bf16x8 af[MR], bfr[4];
#pragma unroll
    for (int m = 0; m < MR; ++m) {
      int rr = wr + m * 16 + (lane & 15);
      af[m] = *reinterpret_cast<const bf16x8*>(&As[rr * 32 + (((lane >> 4) ^ ((rr >> 2) & 3)) << 3)]);
    }
#pragma unroll
    for (int n = 0; n < 4; ++n) {
      int rc = wc + n * 16 + (lane & 15);
      bfr[n] = *reinterpret_cast<const bf16x8*>(&Bs[rc * 32 + (((lane >> 4) ^ ((rc >> 2) & 3)) << 3)]);
    }
#pragma unroll
    for (int m = 0; m < MR; ++m)
#pragma unroll
      for (int n = 0; n < 4; ++n)
        acc[m][n] = __builtin_amdgcn_mfma_f32_16x16x32_bf16(af[m], bfr[n], acc[m][n], 0, 0, 0);
  }

#pragma unroll
  for (int m = 0; m < MR; ++m) {
#pragma unroll
    for (int n = 0; n < 4; ++n) {
      int col = bcol + wc + n * 16 + (lane & 15);
#pragma unroll
      for (int r = 0; r < 4; ++r) {
        int row = brow + wr + m * 16 + ((lane >> 4) << 2) + r;
        float v = acc[m][n][r];
        if (OUTBF) ((bf16_t*)Cout)[(size_t)row * N + col] = (bf16_t)v;
        else       ((float*)Cout)[(size_t)row * N + col] = v;
      }
    }
  }
}

// ---------------- out_proj split-K GEMM: P[split] (bf16) = yB * W_out^T over K-slice ----------------
__global__ __launch_bounds__(256) void k_gemmsk(const bf16_t* __restrict__ A, const bf16_t* __restrict__ Bt,
                                                bf16_t* __restrict__ P) {
  constexpr int BM = 128, BN = 128, K = 2048, N = 1024, KSP = 512;
  __shared__ bf16_t As[BM * 32];
  __shared__ bf16_t Bs[BN * 32];
  const int tid = threadIdx.x, w = tid >> 6, lane = tid & 63;
  const int nbx = gridDim.x;
  int nwg = gridDim.x * gridDim.y;
  int orig = blockIdx.y * gridDim.x + blockIdx.x;
  int cpx = nwg >> 3;
  int swz = (orig & 7) * cpx + (orig >> 3);
  int bx = swz % nbx, byf = swz / nbx;
  const int split = byf & 3, by = byf >> 2;
  const int brow = by * BM, bcol = bx * BN;
  const int wr = (w >> 1) * 64, wc = (w & 1) * 64;
  const int k0 = split * KSP;

  const bf16_t* gsrc[4];
  bf16_t* lbase[4];
#pragma unroll
  for (int i = 0; i < 4; ++i) {
    int p0 = i * 256 + w * 64;
    int p = p0 + lane;
    if (p0 < BM * 4) {
      int r = p >> 2, s = (p & 3) ^ ((r >> 2) & 3);
      gsrc[i] = A + (size_t)(brow + r) * K + s * 8;
      lbase[i] = &As[p0 * 8];
    } else {
      int q = p - BM * 4;
      int r = q >> 2, s = (q & 3) ^ ((r >> 2) & 3);
      gsrc[i] = Bt + (size_t)(bcol + r) * K + s * 8;
      lbase[i] = &Bs[(p0 - BM * 4) * 8];
    }
  }

  f32x4 acc[4][4] = {};
  for (int kk = k0; kk < k0 + KSP; kk += 32) {
    __syncthreads();
#pragma unroll
    for (int i = 0; i < 4; ++i) gload16(gsrc[i] + kk, lbase[i]);
    __syncthreads();
    bf16x8 af[4], bfr[4];
#pragma unroll
    for (int m = 0; m < 4; ++m) {
      int rr = wr + m * 16 + (lane & 15);
      af[m] = *reinterpret_cast<const bf16x8*>(&As[rr * 32 + (((lane >> 4) ^ ((rr >> 2) & 3)) << 3)]);
    }
#pragma unroll
    for (int n = 0; n < 4; ++n) {
      int rc = wc + n * 16 + (lane & 15);
      bfr[n] = *reinterpret_cast<const bf16x8*>(&Bs[rc * 32 + (((lane >> 4) ^ ((rc >> 2) & 3)) << 3)]);
    }
#pragma unroll
    for (int m = 0; m < 4; ++m)
#pragma unroll
      for (int n = 0; n < 4; ++n)
        acc[m][n] = __builtin_amdgcn_mfma_f32_16x16x32_bf16(af[m], bfr[n], acc[m][n], 0, 0, 0);
  }

  bf16_t* Pp = P + (size_t)split * ((size_t)NTOK * N);
#pragma unroll
  for (int m = 0; m < 4; ++m)
#pragma unroll
    for (int n = 0; n < 4; ++n) {
      int col = bcol + wc + n * 16 + (lane & 15);
#pragma unroll
      for (int r = 0; r < 4; ++r) {
        int row = brow + wr + m * 16 + ((lane >> 4) << 2) + r;
        Pp[(size_t)row * N + col] = (bf16_t)acc[m][n][r];
      }
    }
}

// ---------------- split-K reduce (bf16 partials) + residual -> fp32 out ----------------
__global__ __launch_bounds__(256) void k_red(const bf16_t* __restrict__ P, const float* __restrict__ x,
                                             float* __restrict__ out) {
  int i = blockIdx.x * 256 + threadIdx.x;   // bf16x8 index over NTOK*1024/8
  constexpr size_t S8 = (size_t)NTOK * 1024 / 8;
  bf16x8 a = reinterpret_cast<const bf16x8*>(P)[i];
  bf16x8 b = reinterpret_cast<const bf16x8*>(P)[i + S8];
  bf16x8 c = reinterpret_cast<const bf16x8*>(P)[i + 2 * S8];
  bf16x8 d = reinterpret_cast<const bf16x8*>(P)[i + 3 * S8];
  float4 x0 = reinterpret_cast<const float4*>(x)[2 * i];
  float4 x1 = reinterpret_cast<const float4*>(x)[2 * i + 1];
  float xv[8] = { x0.x, x0.y, x0.z, x0.w, x1.x, x1.y, x1.z, x1.w };
  float o[8];
#pragma unroll
  for (int j = 0; j < 8; ++j)
    o[j] = (float)a[j] + (float)b[j] + (float)c[j] + (float)d[j] + xv[j];
  float4 o0 = { o[0], o[1], o[2], o[3] };
  float4 o1 = { o[4], o[5], o[6], o[7] };
  reinterpret_cast<float4*>(out)[2 * i] = o0;
  reinterpret_cast<float4*>(out)[2 * i + 1] = o1;
}

// ---------------- depthwise causal conv1d + SiLU (bf16 in, bf16 out) ----------------
__global__ __launch_bounds__(256) void k_conv(const bf16_t* __restrict__ xz, const float* __restrict__ cw,
                                              const float* __restrict__ cb, bf16_t* __restrict__ xsB) {
  int gid = blockIdx.x * 256 + threadIdx.x;
  int c = gid & (DINNER - 1);
  int t = gid >> 11;
  int l = t & (LSEQ - 1);
  float4 w4 = reinterpret_cast<const float4*>(cw)[c];
  float wk[4] = { w4.x, w4.y, w4.z, w4.w };
  float v = cb[c];
#pragma unroll
  for (int k = 0; k < 4; ++k) {
    int ll = l + k - 3;
    if (ll >= 0) v += wk[k] * (float)xz[(size_t)(t + k - 3) * 4096 + c];
  }
  float sv = v / (1.f + __expf(-v));
  xsB[(size_t)t * DINNER + c] = (bf16_t)sv;
}

// ---------------- x_proj: xdbl[2048][96] = xs(bf16) @ W_x^T, K split across 4 waves ----------------
__global__ __launch_bounds__(256) void k_xproj(const bf16_t* __restrict__ A, const bf16_t* __restrict__ Bt,
                                               float* __restrict__ C) {
  __shared__ f32x4 red[4][6][64];
  int tid = threadIdx.x, w = tid >> 6, lane = tid & 63;
  int r0 = blockIdx.x * 16;
  int arow = r0 + (lane & 15);
  int kof = (lane >> 4) * 8;
  f32x4 acc[6] = {};
  for (int k = w * 512; k < (w + 1) * 512; k += 32) {
    bf16x8 af = *reinterpret_cast<const bf16x8*>(A + (size_t)arow * DINNER + k + kof);
#pragma unroll
    for (int j = 0; j < 6; ++j) {
      bf16x8 bfr = *reinterpret_cast<const bf16x8*>(Bt + (size_t)(j * 16 + (lane & 15)) * DINNER + k + kof);
      acc[j] = __builtin_amdgcn_mfma_f32_16x16x32_bf16(af, bfr, acc[j], 0, 0, 0);
    }
  }
#pragma unroll
  for (int j = 0; j < 6; ++j) red[w][j][lane] = acc[j];
  __syncthreads();
  for (int item = tid; item < 384; item += 256) {
    int j = item >> 6, li = item & 63;
    f32x4 s = red[0][j][li];
#pragma unroll
    for (int ww = 1; ww < 4; ++ww) s += red[ww][j][li];
    int col = j * 16 + (li & 15);
    int rowb = r0 + ((li >> 4) << 2);
#pragma unroll
    for (int r = 0; r < 4; ++r) C[(size_t)(rowb + r) * NXD + col] = s[r];
  }
}

// ---------------- dt_proj (K=64) + softplus -> bf16 ----------------
__global__ __launch_bounds__(256) void k_dtproj(const float* __restrict__ xdbl, const bf16_t* __restrict__ Wdt,
                                                const float* __restrict__ bdt, bf16_t* __restrict__ dtf) {
  int tid = threadIdx.x, w = tid >> 6, lane = tid & 63;
  int r0 = blockIdx.y * 64 + w * 16;
  int c0 = blockIdx.x * 64;
  int arow = r0 + (lane & 15);
  int kof = (lane >> 4) * 8;
  f32x4 acc[4] = {};
#pragma unroll
  for (int ks = 0; ks < 2; ++ks) {
    int k = ks * 32;
    const float* ap = xdbl + (size_t)arow * NXD + k + kof;
    float4 a0 = *reinterpret_cast<const float4*>(ap);
    float4 a1 = *reinterpret_cast<const float4*>(ap + 4);
    bf16x8 af = { (bf16_t)a0.x, (bf16_t)a0.y, (bf16_t)a0.z, (bf16_t)a0.w,
                  (bf16_t)a1.x, (bf16_t)a1.y, (bf16_t)a1.z, (bf16_t)a1.w };
#pragma unroll
    for (int j = 0; j < 4; ++j) {
      bf16x8 bfr = *reinterpret_cast<const bf16x8*>(Wdt + (size_t)(c0 + j * 16 + (lane & 15)) * DTRANK + k + kof);
      acc[j] = __builtin_amdgcn_mfma_f32_16x16x32_bf16(af, bfr, acc[j], 0, 0, 0);
    }
  }
#pragma unroll
  for (int j = 0; j < 4; ++j) {
    int col = c0 + j * 16 + (lane & 15);
    float bb = bdt[col];
#pragma unroll
    for (int r = 0; r < 4; ++r) {
      int row = r0 + ((lane >> 4) << 2) + r;
      float v = acc[j][r] + bb;
      v = (v > 20.f) ? v : log1pf(__expf(v));
      dtf[(size_t)row * DINNER + col] = (bf16_t)v;
    }
  }
}

// ---------------- scan pass A: per-chunk (prod dA, local h) -> packed bf16x2 summaries ----------------
__global__ __launch_bounds__(256) void k_scanA(const bf16_t* __restrict__ dtf, const bf16_t* __restrict__ xs,
                                               const float* __restrict__ xdbl, const float* __restrict__ A_log,
                                               u32* __restrict__ SS) {
  int gid = blockIdx.x * 256 + threadIdx.x;
  int c = gid & (DINNER - 1);
  int chunk = (gid >> 11) & (NC - 1);
  int b = gid >> 17;
  int t0 = b * LSEQ + chunk * CL;
  float dt16[CL], xv16[CL];
#pragma unroll
  for (int l = 0; l < CL; ++l) {
    dt16[l] = (float)dtf[(size_t)(t0 + l) * DINNER + c];
    xv16[l] = (float)xs[(size_t)(t0 + l) * DINNER + c];
  }
  float a[16];
#pragma unroll
  for (int n = 0; n < 16; n += 4) {
    float4 al = reinterpret_cast<const float4*>(A_log + (size_t)c * 16)[n >> 2];
    a[n] = -__expf(al.x); a[n + 1] = -__expf(al.y); a[n + 2] = -__expf(al.z); a[n + 3] = -__expf(al.w);
  }
  float ap[16], h[16];
#pragma unroll
  for (int n = 0; n < 16; ++n) { ap[n] = 1.f; h[n] = 0.f; }
#pragma unroll
  for (int l = 0; l < CL; ++l) {
    int t = t0 + l;
    float dt = dt16[l];
    float dtx = dt * xv16[l];
    const float4* bp = reinterpret_cast<const float4*>(xdbl + (size_t)t * NXD + DTRANK);
    float4 b0 = bp[0], b1 = bp[1], b2 = bp[2], b3 = bp[3];
    float bv[16] = { b0.x, b0.y, b0.z, b0.w, b1.x, b1.y, b1.z, b1.w,
                     b2.x, b2.y, b2.z, b2.w, b3.x, b3.y, b3.z, b3.w };
#pragma unroll
    for (int n = 0; n < 16; ++n) {
      float e = __expf(dt * a[n]);
      ap[n] *= e;
      h[n] = e * h[n] + dtx * bv[n];
    }
  }
  size_t base = ((size_t)(b * NC + chunk) * 16) * DINNER + c;
#pragma unroll
  for (int n = 0; n < 16; ++n)
    SS[base + (size_t)n * DINNER] = pack2(ap[n], h[n]);
}

// ---------------- scan pass B: combine packed summaries -> bf16 h_init per chunk ----------------
__global__ __launch_bounds__(256) void k_scanB(const u32* __restrict__ SS, bf16_t* __restrict__ Hi) {
  int gid = blockIdx.x * 256 + threadIdx.x;
  int c = gid & (DINNER - 1);
  int n = (gid >> 11) & 15;
  int b = gid >> 15;
  size_t idx = ((size_t)(b * NC) * 16 + n) * DINNER + c;
  const size_t stride = (size_t)16 * DINNER;
  float h = 0.f;
#pragma unroll 4
  for (int chunk = 0; chunk < NC; ++chunk) {
    Hi[idx] = (bf16_t)h;
    u32 v = SS[idx];
    h = lo2f(v) * h + hi2f(v);
    idx += stride;
  }
}

// ---------------- scan pass C: replay with bf16 h_init, fuse y + gate -> y bf16 ----------------
__global__ __launch_bounds__(256) void k_scanC(const bf16_t* __restrict__ dtf, const bf16_t* __restrict__ xs,
                                               const float* __restrict__ xdbl, const float* __restrict__ A_log,
                                               const bf16_t* __restrict__ Hi, const float* __restrict__ Dp,
                                               const bf16_t* __restrict__ xz, bf16_t* __restrict__ yB) {
  int gid = blockIdx.x * 256 + threadIdx.x;
  int c = gid & (DINNER - 1);
  int chunk = (gid >> 11) & (NC - 1);
  int b = gid >> 17;
  int t0 = b * LSEQ + chunk * CL;
  float dt16[CL], xv16[CL], zv16[CL];
#pragma unroll
  for (int l = 0; l < CL; ++l) {
    dt16[l] = (float)dtf[(size_t)(t0 + l) * DINNER + c];
    xv16[l] = (float)xs[(size_t)(t0 + l) * DINNER + c];
    zv16[l] = (float)xz[(size_t)(t0 + l) * 4096 + DINNER + c];
  }
  float a[16];
#pragma unroll
  for (int n = 0; n < 16; n += 4) {
    float4 al = reinterpret_cast<const float4*>(A_log + (size_t)c * 16)[n >> 2];
    a[n] = -__expf(al.x); a[n + 1] = -__expf(al.y); a[n + 2] = -__expf(al.z); a[n + 3] = -__expf(al.w);
  }
  float h[16];
  size_t base = ((size_t)(b * NC + chunk) * 16) * DINNER + c;
#pragma unroll
  for (int n = 0; n < 16; ++n) h[n] = (float)Hi[base + (size_t)n * DINNER];
  float dpc = Dp[c];
#pragma unroll
  for (int l = 0; l < CL; ++l) {
    int t = t0 + l;
    float dt = dt16[l];
    float xv = xv16[l];
    float zv = zv16[l];
    float dtx = dt * xv;
    const float4* bp = reinterpret_cast<const float4*>(xdbl + (size_t)t * NXD + DTRANK);
    float4 b0 = bp[0], b1 = bp[1], b2 = bp[2], b3 = bp[3];
    float bv[16] = { b0.x, b0.y, b0.z, b0.w, b1.x, b1.y, b1.z, b1.w,
                     b2.x, b2.y, b2.z, b2.w, b3.x, b3.y, b3.z, b3.w };
    const float4* cp = reinterpret_cast<const float4*>(xdbl + (size_t)t * NXD + DTRANK + 16);
    float4 c0 = cp[0], c1 = cp[1], c2 = cp[2], c3 = cp[3];
    float cv[16] = { c0.x, c0.y, c0.z, c0.w, c1.x, c1.y, c1.z, c1.w,
                     c2.x, c2.y, c2.z, c2.w, c3.x, c3.y, c3.z, c3.w };
    float y = 0.f;
#pragma unroll
    for (int n = 0; n < 16; ++n) {
      float e = __expf(dt * a[n]);
      h[n] = e * h[n] + dtx * bv[n];
      y += h[n] * cv[n];
    }
    y += dpc * xv;
    y *= zv / (1.f + __expf(-zv));
    yB[(size_t)t * DINNER + c] = (bf16_t)y;
  }
}

extern "C" void kernel_launch(void* const* d_in, const int* in_sizes, int n_in,
                              void* d_out, int out_size, void* d_ws, size_t ws_size,
                              hipStream_t stream) {
  (void)in_sizes; (void)n_in; (void)out_size; (void)ws_size;
  const float* x      = (const float*)d_in[0];
  const float* ln_w   = (const float*)d_in[1];
  const float* ln_b   = (const float*)d_in[2];
  const float* W_in   = (const float*)d_in[3];
  const float* conv_w = (const float*)d_in[4];
  const float* conv_b = (const float*)d_in[5];
  const float* W_x    = (const float*)d_in[6];
  const float* W_dt   = (const float*)d_in[7];
  const float* b_dt   = (const float*)d_in[8];
  const float* A_log  = (const float*)d_in[9];
  const float* Dp     = (const float*)d_in[10];
  const float* W_out  = (const float*)d_in[11];
  float* out = (float*)d_out;

  char* ws = (char*)d_ws;
  size_t off = 0;
  auto alloc = [&](size_t bytes) { void* p = ws + off; off += (bytes + 255) & ~255ull; return p; };
  bf16_t* wInB  = (bf16_t*)alloc((size_t)4096 * 1024 * 2);
  bf16_t* wXB   = (bf16_t*)alloc((size_t)96 * 2048 * 2);
  bf16_t* wDtB  = (bf16_t*)alloc((size_t)2048 * 64 * 2);
  bf16_t* wOutB = (bf16_t*)alloc((size_t)1024 * 2048 * 2);
  bf16_t* xnB   = (bf16_t*)alloc((size_t)NTOK * DMODEL * 2);
  bf16_t* xzB   = (bf16_t*)alloc((size_t)NTOK * 4096 * 2);
  bf16_t* xsB   = (bf16_t*)alloc((size_t)NTOK * DINNER * 2);
  float*  xdbl  = (float*)alloc((size_t)NTOK * NXD * 4);
  bf16_t* dtfB  = (bf16_t*)alloc((size_t)NTOK * DINNER * 2);
  u32*    SS    = (u32*)alloc((size_t)2 * NC * 16 * DINNER * 4);
  bf16_t* HiB   = (bf16_t*)alloc((size_t)2 * NC * 16 * DINNER * 2);
  bf16_t* yB    = (bf16_t*)alloc((size_t)NTOK * DINNER * 2);
  bf16_t* Pq    = (bf16_t*)alloc((size_t)4 * NTOK * 1024 * 2);   // split-K partials (bf16)

  // fused layernorm + weight conversion (1 launch)
  k_lncvt<<<NTOK + CVT_N3 / 256, 256, 0, stream>>>(x, ln_w, ln_b, xnB,
                                                   W_in, W_x, W_dt, W_out, wInB, wXB, wDtB, wOutB);

  // in_proj: xz[2048][4096] bf16
  k_gemm<128, true><<<dim3(4096 / 128, NTOK / 128), 256, 0, stream>>>(xnB, wInB, xzB, 4096, 1024);

  // conv + silu (bf16 out only)
  k_conv<<<NTOK * DINNER / 256, 256, 0, stream>>>(xzB, conv_w, conv_b, xsB);

  // x_proj (K-split across 4 waves)
  k_xproj<<<NTOK / 16, 256, 0, stream>>>(xsB, wXB, xdbl);

  // dt_proj + softplus -> bf16
  k_dtproj<<<dim3(DINNER / 64, NTOK / 64), 256, 0, stream>>>(xdbl, wDtB, b_dt, dtfB);

  // chunked scan (NC=64 -> 1024 blocks for A/C), packed bf16x2 summaries
  k_scanA<<<2 * NC * DINNER / 256, 256, 0, stream>>>(dtfB, xsB, xdbl, A_log, SS);
  k_scanB<<<2 * 16 * DINNER / 256, 256, 0, stream>>>(SS, HiB);
  k_scanC<<<2 * NC * DINNER / 256, 256, 0, stream>>>(dtfB, xsB, xdbl, A_log, HiB, Dp, xzB, yB);

  // out_proj: split-K x4 (512 WGs) -> bf16 partials + reduce with residual
  k_gemmsk<<<dim3(8, 64), 256, 0, stream>>>(yB, wOutB, Pq);
  k_red<<<NTOK * 1024 / 8 / 256, 256, 0, stream>>>(Pq, x, out);
}